// Round 1
// 4887.469 us; speedup vs baseline: 1.0588x; 1.0588x over previous
//
#include <hip/hip_runtime.h>
#include <math.h>

// ---------------------------------------------------------------------------
// Sender: LSTM + Gumbel straight-through decode, 32 steps.
// Round 9 (from r8, 4758-5175 us):
//  (1) Double-buffered LDS K-loop: prefetch tile k+1 (global_load_lds issued)
//      BEFORE computing tile k; ONE __syncthreads per K-step (its implicit
//      vmcnt(0) drain lands after a full compute phase of cover). r8 was
//      stage/barrier/compute/barrier - global latency fully exposed at only
//      2 blocks/CU of TLP.
//  (2) K-slot XOR swizzle: LDS dest stays linear (global_load_lds writes
//      base+lane*16); the global SOURCE 16B-slot and the ds_read slot are
//      both XORed with ((row>>1)&3). Fragment ds_read_b128 was an 8-way
//      bank conflict (64B row stride, fixed 16B col across 16 rows); now
//      2-way (free). Both XORs fold to per-lane compile-time constants.
//  (3) sc = (1-y)+y == 1.0f exactly for any f32 y in (0,1] (Sterbenz /
//      half-ulp rounding) in BOTH this kernel and the JAX reference, so the
//      softmax denominator (partS + expf reduce) is dead code: finalize is
//      argmax-only; output rows are exact {0,1} one-hots.
// MFMA math/order identical to r8 (f16 2-way split, 3 MFMA/product).
// ---------------------------------------------------------------------------

typedef _Float16 f16;
typedef f16 f16x8 __attribute__((ext_vector_type(8)));
typedef float f32x4 __attribute__((ext_vector_type(4)));

#define F16_MIN_NORM 6.104e-5f

__device__ __forceinline__ void split_f16(float v, f16& h, f16& l) {
  f16 h0 = (fabsf(v) < F16_MIN_NORM) ? (f16)0.0f : (f16)v;
  float r = (v - (float)h0) * 4096.0f;
  h = h0; l = (f16)r;
}

__device__ __forceinline__ float sigm(float x) { return 1.0f / (1.0f + expf(-x)); }

#define GLOAD_LDS16(gsrc, ldst)                                               \
  __builtin_amdgcn_global_load_lds(                                           \
      (const __attribute__((address_space(1))) unsigned int*)(const void*)(gsrc), \
      (__attribute__((address_space(3))) unsigned int*)(void*)(ldst), 16, 0, 0)

// --------------------------- threefry / gumbel -----------------------------

__device__ __forceinline__ unsigned tf_rotl(unsigned x, int r) {
  return (x << r) | (x >> (32 - r));
}

// JAX threefry2x32-20, key (0,42), partitionable: draw = x0_out ^ x1_out.
__device__ inline float gumbel_at(unsigned idx) {
  const unsigned ks0 = 0u;
  const unsigned ks1 = 42u;
  const unsigned ks2 = 0x1BD11BDAu ^ ks0 ^ ks1;
  unsigned x0 = 0u + ks0;
  unsigned x1 = idx + ks1;
#define TFR(rot) { x0 += x1; x1 = tf_rotl(x1, rot); x1 ^= x0; }
  TFR(13) TFR(15) TFR(26) TFR(6)
  x0 += ks1; x1 += ks2 + 1u;
  TFR(17) TFR(29) TFR(16) TFR(24)
  x0 += ks2; x1 += ks0 + 2u;
  TFR(13) TFR(15) TFR(26) TFR(6)
  x0 += ks0; x1 += ks1 + 3u;
  TFR(17) TFR(29) TFR(16) TFR(24)
  x0 += ks1; x1 += ks2 + 4u;
  TFR(13) TFR(15) TFR(26) TFR(6)
  x0 += ks2; x1 += ks0 + 5u;
#undef TFR
  const unsigned bits = x0 ^ x1;
  const float f = __uint_as_float((bits >> 9) | 0x3F800000u) - 1.0f;
  const float tiny = 1.17549435082228751e-38f;
  const float u = fmaxf(tiny, f * (1.0f - tiny) + tiny);
  return -logf(-logf(u));
}

// ------------------------- setup / pack kernels ----------------------------

__global__ void init_kernel(float* __restrict__ out, const float* __restrict__ emb,
                            f16* __restrict__ e0, f16* __restrict__ e1,
                            const int* __restrict__ startp, int Tp1, int V, int E) {
  const int b = blockIdx.x;
  const int start = *startp;
  float* orow = out + (size_t)b * Tp1 * V;
  const int tq = start >> 2;
  for (int v4 = threadIdx.x; v4 < V / 4; v4 += blockDim.x) {
    float4 v = make_float4(0.f, 0.f, 0.f, 0.f);
    if (v4 == tq) ((float*)&v)[start & 3] = 1.0f;
    ((float4*)orow)[v4] = v;
  }
  if (threadIdx.x < E) {
    const float v = emb[(size_t)start * E + threadIdx.x];
    f16 h, l; split_f16(v, h, l);
    e0[(size_t)b * E + threadIdx.x] = h;
    e1[(size_t)b * E + threadIdx.x] = l;
  }
}

// packed gate col p: gate q=(p>>4)&3, unit u=((p>>6)<<4)+(p&15); orig row
// n' = q*H + u. wpk[p][k] = k<E ? wih[n'][k] : whh[n'][k-E], split.
__global__ void pack_gates_kernel(const float* __restrict__ wih,
                                  const float* __restrict__ whh,
                                  f16* __restrict__ w0, f16* __restrict__ w1,
                                  int E, int H, int K) {
  const int k = blockIdx.x * blockDim.x + threadIdx.x;
  const int p = blockIdx.y;
  if (k >= K) return;
  const int n = ((p >> 4) & 3) * H + ((p >> 6) << 4) + (p & 15);
  const float v = (k < E) ? wih[(size_t)n * E + k] : whh[(size_t)n * H + (k - E)];
  f16 h, l; split_f16(v, h, l);
  w0[(size_t)p * K + k] = h;
  w1[(size_t)p * K + k] = l;
}

__global__ void pack_bias_kernel(const float* __restrict__ bih,
                                 const float* __restrict__ bhh,
                                 float* __restrict__ bi, float* __restrict__ bh, int H) {
  const int p = blockIdx.x * blockDim.x + threadIdx.x;
  const int n = ((p >> 4) & 3) * H + ((p >> 6) << 4) + (p & 15);
  bi[p] = bih[n];
  bh[p] = bhh[n];
}

__global__ void split_kernel(const float* __restrict__ in,
                             f16* __restrict__ o0, f16* __restrict__ o1, int n) {
  const int i = blockIdx.x * blockDim.x + threadIdx.x;
  if (i < n) { f16 h, l; split_f16(in[i], h, l); o0[i] = h; o1[i] = l; }
}

// ----------------------- shared K-loop building block ----------------------
// block 256 thr / 4 waves, tile 128x64, BK=32, double-buffered LDS (48 KB).
// Staging: 24 1KB chunks (A-hi 8, A-lo 8, B-hi 4, B-lo 4), 6 per wave.
// Wave w computes rows [w*32, w*32+32) x all 64 cols.
// Swizzle: LDS[row][slot] holds global 16B-slot (slot ^ ((row>>1)&3)).
//   stage source slot = (lane&3) ^ ((lane>>3)&3)   (srow = lane>>2)
//   read slot         = (lane>>4) ^ ((lane>>1)&3)  (row & 15 == lane & 15)
// Both per-lane constants; 4-lane source groups still cover one contiguous
// 64B row segment -> coalescing unchanged.

__device__ __forceinline__ void stage_chunk(
    int chunk, int srow, int scol,
    const f16* __restrict__ a0s, const f16* __restrict__ a1s, int lda, int ka, int bm,
    const f16* __restrict__ b0s, const f16* __restrict__ b1s, int ldb, int kb, int bn,
    f16 (*ldsA0)[32], f16 (*ldsA1)[32], f16 (*ldsB0)[32], f16 (*ldsB1)[32])
{
  if (chunk < 8) {
    GLOAD_LDS16(a0s + (size_t)(bm + chunk * 16 + srow) * lda + ka + scol,
                &ldsA0[chunk * 16][0]);
  } else if (chunk < 16) {
    const int s = chunk - 8;
    GLOAD_LDS16(a1s + (size_t)(bm + s * 16 + srow) * lda + ka + scol,
                &ldsA1[s * 16][0]);
  } else if (chunk < 20) {
    const int s = chunk - 16;
    GLOAD_LDS16(b0s + (size_t)(bn + s * 16 + srow) * ldb + kb + scol,
                &ldsB0[s * 16][0]);
  } else {
    const int s = chunk - 20;
    GLOAD_LDS16(b1s + (size_t)(bn + s * 16 + srow) * ldb + kb + scol,
                &ldsB1[s * 16][0]);
  }
}

#define MFMA_DECLS                                                            \
  const int tid  = threadIdx.x;                                               \
  const int lane = tid & 63;                                                  \
  const int wid  = tid >> 6;                                                  \
  const int bm   = blockIdx.y * 128;                                          \
  const int bn   = blockIdx.x * 64;                                           \
  const int wm   = wid * 32;                                                  \
  const int fr   = lane & 15;                                                 \
  const int fk   = (((lane >> 4) ^ ((lane >> 1) & 3)) * 8);                   \
  const int srow = lane >> 2;                                                 \
  const int scol = (((lane & 3) ^ ((lane >> 3) & 3)) * 8);                    \
  f32x4 acc0[2][4], acc1[2][4];                                               \
  _Pragma("unroll") for (int i = 0; i < 2; ++i)                               \
  _Pragma("unroll") for (int j = 0; j < 4; ++j) {                             \
    acc0[i][j] = (f32x4)0.0f; acc1[i][j] = (f32x4)0.0f; }

// Issue-only staging into buffer `buf` (no barriers here).
#define MFMA_STAGE_TO(buf, a0s, a1s, lda, ka, b0s, b1s, ldb, kb)              \
  { _Pragma("unroll") for (int c = 0; c < 6; ++c)                             \
      stage_chunk(wid * 6 + c, srow, scol, (a0s), (a1s), (lda), (ka), bm,     \
                  (b0s), (b1s), (ldb), (kb), bn,                              \
                  ldsA0[buf], ldsA1[buf], ldsB0[buf], ldsB1[buf]); }

#define MFMA_COMPUTE_FROM(buf)                                                \
  {                                                                           \
    f16x8 a0[2], a1[2], b0[4], b1[4];                                         \
    _Pragma("unroll") for (int i = 0; i < 2; ++i) {                           \
      a0[i] = *(const f16x8*)&ldsA0[buf][wm + i * 16 + fr][fk];               \
      a1[i] = *(const f16x8*)&ldsA1[buf][wm + i * 16 + fr][fk];               \
    }                                                                         \
    _Pragma("unroll") for (int j = 0; j < 4; ++j) {                           \
      b0[j] = *(const f16x8*)&ldsB0[buf][j * 16 + fr][fk];                    \
      b1[j] = *(const f16x8*)&ldsB1[buf][j * 16 + fr][fk];                    \
    }                                                                         \
    _Pragma("unroll") for (int i = 0; i < 2; ++i)                             \
    _Pragma("unroll") for (int j = 0; j < 4; ++j) {                           \
      acc0[i][j] = __builtin_amdgcn_mfma_f32_16x16x32_f16(a0[i], b0[j], acc0[i][j], 0, 0, 0); \
      acc1[i][j] = __builtin_amdgcn_mfma_f32_16x16x32_f16(a0[i], b1[j], acc1[i][j], 0, 0, 0); \
      acc1[i][j] = __builtin_amdgcn_mfma_f32_16x16x32_f16(a1[i], b0[j], acc1[i][j], 0, 0, 0); \
    }                                                                         \
  }

#define MFMA_LDS_DECL                                                         \
  __shared__ f16 ldsA0[2][128][32], ldsA1[2][128][32],                        \
                 ldsB0[2][64][32],  ldsB1[2][64][32];

// ------------------- h0 GEMM: h0 = t @ aff_w^T + aff_b ---------------------
__global__ __launch_bounds__(256, 2) void h0_kernel(
    const f16* __restrict__ t0, const f16* __restrict__ t1, int F,
    const f16* __restrict__ aw0, const f16* __restrict__ aw1,
    const float* __restrict__ affb,
    f16* __restrict__ h0p, f16* __restrict__ h1p, int H,
    float* __restrict__ czero)
{
  MFMA_LDS_DECL
  MFMA_DECLS
  MFMA_STAGE_TO(0, t0, t1, F, 0, aw0, aw1, F, 0)
  __syncthreads();
  for (int kk = 0; kk < F; kk += 64) {
    if (kk + 32 < F)
      MFMA_STAGE_TO(1, t0, t1, F, kk + 32, aw0, aw1, F, kk + 32)
    MFMA_COMPUTE_FROM(0)
    __syncthreads();
    if (kk + 64 < F)
      MFMA_STAGE_TO(0, t0, t1, F, kk + 64, aw0, aw1, F, kk + 64)
    MFMA_COMPUTE_FROM(1)
    __syncthreads();
  }
  const int q4 = (lane >> 4) * 4;
  const float s12 = 1.0f / 4096.0f;
#pragma unroll
  for (int j = 0; j < 4; ++j) {
    const int col = bn + j * 16 + fr;
    const float bb = affb[col];
#pragma unroll
    for (int i = 0; i < 2; ++i) {
#pragma unroll
      for (int r = 0; r < 4; ++r) {
        const int row = bm + wm + i * 16 + q4 + r;
        const float v = (acc0[i][j][r] + acc1[i][j][r] * s12) + bb;
        f16 hh, hl; split_f16(v, hh, hl);
        const size_t off = (size_t)row * H + col;
        h0p[off] = hh; h1p[off] = hl;
        czero[off] = 0.0f;
      }
    }
  }
}

// ---------------- gates GEMM + fused LSTM cell epilogue --------------------
__global__ __launch_bounds__(256, 2) void gates_kernel(
    const f16* __restrict__ e0, const f16* __restrict__ e1, int E,
    const f16* __restrict__ hin0, const f16* __restrict__ hin1, int H,
    const f16* __restrict__ w0, const f16* __restrict__ w1, int K,
    const float* __restrict__ bi, const float* __restrict__ bh,
    float* __restrict__ cbuf,
    f16* __restrict__ hout0, f16* __restrict__ hout1)
{
  MFMA_LDS_DECL
  MFMA_DECLS
  MFMA_STAGE_TO(0, e0, e1, E, 0, w0, w1, K, 0)
  __syncthreads();
  for (int kk = 0; kk < K; kk += 64) {
    {
      const int kn = kk + 32;
      if (kn < K) {
        const f16* a0s; const f16* a1s; int lda, ka;
        if (kn < E) { a0s = e0;   a1s = e1;   lda = E; ka = kn; }
        else        { a0s = hin0; a1s = hin1; lda = H; ka = kn - E; }
        MFMA_STAGE_TO(1, a0s, a1s, lda, ka, w0, w1, K, kn)
      }
    }
    MFMA_COMPUTE_FROM(0)
    __syncthreads();
    {
      const int kn = kk + 64;
      if (kn < K) {
        const f16* a0s; const f16* a1s; int lda, ka;
        if (kn < E) { a0s = e0;   a1s = e1;   lda = E; ka = kn; }
        else        { a0s = hin0; a1s = hin1; lda = H; ka = kn - E; }
        MFMA_STAGE_TO(0, a0s, a1s, lda, ka, w0, w1, K, kn)
      }
    }
    MFMA_COMPUTE_FROM(1)
    __syncthreads();
  }
  // epilogue: packed cols -> unit u = (bn>>2)+fr, gate q = j.
  const int q4 = (lane >> 4) * 4;
  const float s12 = 1.0f / 4096.0f;
  float biv[4], bhv[4];
#pragma unroll
  for (int j = 0; j < 4; ++j) {
    const int col = bn + j * 16 + fr;
    biv[j] = bi[col]; bhv[j] = bh[col];
  }
  const int nunit = (bn >> 2) + fr;
#pragma unroll
  for (int i = 0; i < 2; ++i) {
#pragma unroll
    for (int r = 0; r < 4; ++r) {
      const int row = bm + wm + i * 16 + q4 + r;
      float gv[4];
#pragma unroll
      for (int j = 0; j < 4; ++j)
        gv[j] = ((acc0[i][j][r] + acc1[i][j][r] * s12) + biv[j]) + bhv[j];
      const size_t off = (size_t)row * H + nunit;
      const float c = cbuf[off];
      const float cn = __fadd_rn(__fmul_rn(sigm(gv[1]), c),
                                 __fmul_rn(sigm(gv[0]), tanhf(gv[2])));
      const float hn = __fmul_rn(sigm(gv[3]), tanhf(cn));
      cbuf[off] = cn;
      f16 hh, hl; split_f16(hn, hh, hl);
      hout0[off] = hh; hout1[off] = hl;
    }
  }
}

// ------------- logits GEMM + fused argmax-partials epilogue ----------------
__global__ __launch_bounds__(256, 2) void logits_kernel(
    const f16* __restrict__ h0p, const f16* __restrict__ h1p, int H,
    const f16* __restrict__ w0, const f16* __restrict__ w1,
    const float* __restrict__ lpb,
    float* __restrict__ partM, int* __restrict__ partI,
    int step, int B, int V)
{
  MFMA_LDS_DECL
  MFMA_DECLS
  MFMA_STAGE_TO(0, h0p, h1p, H, 0, w0, w1, H, 0)
  __syncthreads();
  for (int kk = 0; kk < H; kk += 64) {
    if (kk + 32 < H)
      MFMA_STAGE_TO(1, h0p, h1p, H, kk + 32, w0, w1, H, kk + 32)
    MFMA_COMPUTE_FROM(0)
    __syncthreads();
    if (kk + 64 < H)
      MFMA_STAGE_TO(0, h0p, h1p, H, kk + 64, w0, w1, H, kk + 64)
    MFMA_COMPUTE_FROM(1)
    __syncthreads();
  }
  const int q4 = (lane >> 4) * 4;
  const float s12 = 1.0f / 4096.0f;
  float bv[4];
#pragma unroll
  for (int j = 0; j < 4; ++j) bv[j] = lpb[bn + j * 16 + fr];
  // w = logit + gumbel, overwrite acc0
#pragma unroll
  for (int i = 0; i < 2; ++i)
#pragma unroll
    for (int j = 0; j < 4; ++j) {
      const int col = bn + j * 16 + fr;
#pragma unroll
      for (int r = 0; r < 4; ++r) {
        const int row = bm + wm + i * 16 + q4 + r;
        const float logit = (acc0[i][j][r] + acc1[i][j][r] * s12) + bv[j];
        const unsigned gidx = ((unsigned)(step * B + row)) * (unsigned)V + (unsigned)col;
        acc0[i][j][r] = logit + gumbel_at(gidx);
      }
    }
  // per-row argmax over this block's 64 cols (within each 16-lane group).
  // sc == 1.0 exactly (see header), so no denominator partials needed.
  const int grp = bn >> 6;   // == blockIdx.x
#pragma unroll
  for (int i = 0; i < 2; ++i) {
#pragma unroll
    for (int r = 0; r < 4; ++r) {
      float mx = -INFINITY; int ix = 0;
#pragma unroll
      for (int j = 0; j < 4; ++j) {
        const float w = acc0[i][j][r];
        const int col = bn + j * 16 + fr;
        if (w > mx) { mx = w; ix = col; }
      }
#pragma unroll
      for (int m = 1; m < 16; m <<= 1) {
        const float om = __shfl_xor(mx, m, 64);
        const int oi = __shfl_xor(ix, m, 64);
        if (om > mx || (om == mx && oi < ix)) { mx = om; ix = oi; }
      }
      if (fr == 0) {
        const int row = bm + wm + i * 16 + q4 + r;
        partM[(size_t)row * 64 + grp] = mx;
        partI[(size_t)row * 64 + grp] = ix;
      }
    }
  }
}

// ---------------- finalize: argmax reduce, write, next emb -----------------
__global__ __launch_bounds__(256) void finalize_kernel(
    const float* __restrict__ partM, const int* __restrict__ partI,
    const float* __restrict__ emb,
    float* __restrict__ out,
    f16* __restrict__ e0, f16* __restrict__ e1,
    int step, int Tp1, int V, int E)
{
  const int b = blockIdx.x;
  const int tid = threadIdx.x;
  __shared__ int s_tok;

  if (tid < 64) {
    float mx = partM[(size_t)b * 64 + tid];
    int ix = partI[(size_t)b * 64 + tid];
#pragma unroll
    for (int m = 1; m < 64; m <<= 1) {
      const float om = __shfl_xor(mx, m, 64);
      const int oi = __shfl_xor(ix, m, 64);
      if (om > mx || (om == mx && oi < ix)) { mx = om; ix = oi; }
    }
    if (tid == 0) s_tok = ix;
  }
  __syncthreads();
  const int tok = s_tok;

  // one-hot write with exact 1.0 (sc == (1-y)+y == 1.0f identically)
  float* orow = out + ((size_t)b * Tp1 + step + 1) * V;
  const int tq = tok >> 2;
#pragma unroll
  for (int j = 0; j < 4; ++j) {
    const int idx = tid + 256 * j;
    float4 v = make_float4(0.f, 0.f, 0.f, 0.f);
    if (idx == tq) ((float*)&v)[tok & 3] = 1.0f;
    ((float4*)orow)[idx] = v;
  }

  if (tid < E) {
    const float ev = emb[(size_t)tok * E + tid];
    f16 h, l; split_f16(ev, h, l);
    e0[(size_t)b * E + tid] = h;
    e1[(size_t)b * E + tid] = l;
  }
}

// ------------------------------- host side ---------------------------------

extern "C" void kernel_launch(void* const* d_in, const int* in_sizes, int n_in,
                              void* d_out, int out_size, void* d_ws, size_t ws_size,
                              hipStream_t stream) {
  const float* t     = (const float*)d_in[0];
  const float* emb   = (const float*)d_in[1];
  const float* affw  = (const float*)d_in[2];
  const float* affb  = (const float*)d_in[3];
  const float* wih   = (const float*)d_in[4];
  const float* whh   = (const float*)d_in[5];
  const float* bih   = (const float*)d_in[6];
  const float* bhh   = (const float*)d_in[7];
  const float* lpw   = (const float*)d_in[8];
  const float* lpb   = (const float*)d_in[9];
  const int*   start = (const int*)d_in[10];
  float* out = (float*)d_out;

  const int H = in_sizes[3];             // 1024
  const int V = in_sizes[9];             // 4096
  const int E = in_sizes[1] / V;         // 256
  const int F = in_sizes[2] / H;         // 2048
  const int B = in_sizes[0] / F;         // 1024
  const int Tp1 = out_size / (B * V);    // 33
  const int T = Tp1 - 1;                 // 32
  const int KG = E + H;                  // 1280

  // ---- workspace layout (~65 MB) ----
  char* p = (char*)d_ws;
  float* cbuf  = (float*)p; p += (size_t)B * H * 4;           // 4 MB
  f16* hA0[2]; f16* hA1[2];
  hA0[0] = (f16*)p; p += (size_t)B * H * 2;
  hA1[0] = (f16*)p; p += (size_t)B * H * 2;
  hA0[1] = (f16*)p; p += (size_t)B * H * 2;
  hA1[1] = (f16*)p; p += (size_t)B * H * 2;                   // 8 MB
  f16* embA0 = (f16*)p; p += (size_t)B * E * 2;
  f16* embA1 = (f16*)p; p += (size_t)B * E * 2;               // 1 MB
  f16* wg0 = (f16*)p; p += (size_t)V * KG * 2;                // 20 MB packed gates
  f16* wg1 = (f16*)p; p += (size_t)V * KG * 2;
  f16* wl0 = (f16*)p; p += (size_t)V * H * 2;                 // 16 MB lp_w
  f16* wl1 = (f16*)p; p += (size_t)V * H * 2;
  f16* t0  = (f16*)p; p += (size_t)B * F * 2;                 // 8 MB t planes
  f16* t1  = (f16*)p; p += (size_t)B * F * 2;
  f16* aw0 = (f16*)p; p += (size_t)H * F * 2;                 // 8 MB aff_w planes
  f16* aw1 = (f16*)p; p += (size_t)H * F * 2;
  float* bgi = (float*)p; p += (size_t)V * 4;
  float* bgh = (float*)p; p += (size_t)V * 4;
  float* partM = (float*)p; p += (size_t)B * 64 * 4;
  int*   partI = (int*)p;   p += (size_t)B * 64 * 4;
  (void)ws_size; (void)n_in;

  // ---- setup ----
  init_kernel<<<B, 256, 0, stream>>>(out, emb, embA0, embA1, start, Tp1, V, E);
  pack_gates_kernel<<<dim3((KG + 255) / 256, V), 256, 0, stream>>>(
      wih, whh, wg0, wg1, E, H, KG);
  pack_bias_kernel<<<V / 256, 256, 0, stream>>>(bih, bhh, bgi, bgh, H);
  split_kernel<<<(V * H + 255) / 256, 256, 0, stream>>>(lpw, wl0, wl1, V * H);
  split_kernel<<<(B * F + 255) / 256, 256, 0, stream>>>(t, t0, t1, B * F);
  split_kernel<<<(H * F + 255) / 256, 256, 0, stream>>>(affw, aw0, aw1, H * F);
  // h0 = t @ aff_w^T + aff_b -> split into hA[0]; zero cbuf
  h0_kernel<<<dim3(H / 64, B / 128), 256, 0, stream>>>(
      t0, t1, F, aw0, aw1, affb, hA0[0], hA1[0], H, cbuf);

  for (int s = 0; s < T; ++s) {
    const int cur = s & 1, nxt = (s + 1) & 1;
    gates_kernel<<<dim3(V / 64, B / 128), 256, 0, stream>>>(
        embA0, embA1, E, hA0[cur], hA1[cur], H,
        wg0, wg1, KG, bgi, bgh, cbuf, hA0[nxt], hA1[nxt]);
    logits_kernel<<<dim3(V / 64, B / 128), 256, 0, stream>>>(
        hA0[nxt], hA1[nxt], H, wl0, wl1, lpb,
        partM, partI, s, B, V);
    finalize_kernel<<<B, 256, 0, stream>>>(
        partM, partI, emb, out, embA0, embA1, s, Tp1, V, E);
  }
}

// Round 2
// 3967.503 us; speedup vs baseline: 1.3043x; 1.2319x over previous
//
#include <hip/hip_runtime.h>
#include <math.h>

// ---------------------------------------------------------------------------
// Sender: LSTM + Gumbel straight-through decode, 32 steps.
// Round 10 (from r9, 4887 us):
//  (1) gih table: tok is an exact one-hot (sc==1.0), so the embedding term
//      of the gates GEMM is a lookup. Precompute once
//        gih[v][p] = emb[v] . w_ih[n(p)] + b_ih[n(p)] + b_hh[n(p)]   (f32)
//      via the same MFMA structure (K=E=256). Per-step gates GEMM drops to
//      K=H=1024 (-20% MFMA+staging) + a 64B/row gather in the epilogue.
//      finalize now just publishes tok[b]; embA planes deleted.
//  (2) Triple-buffered K-loop, counted vmcnt (T3/T4): stage tile t+2, then
//      "s_waitcnt vmcnt(12)" (12 = 2 stages x 6 chunks in flight; oldest 6
//      = tile t landed), raw s_barrier, compute, raw s_barrier. Loads get
//      2 compute phases of cover instead of 1; vmcnt never drains to 0 in
//      steady state (r9's __syncthreads forced vmcnt(0) every phase).
//      Compiler fences (asm "" memory) pin global_load_lds / ds_read on the
//      correct side of each raw barrier. LDS 72 KB, still 2 blocks/CU.
//  (3) s_setprio(1) around the MFMA cluster (T5; pipeline creates wave
//      role-split, the regime where setprio pays).
// MFMA math: f16 2-way split (3 MFMA/product), identical fragment layout
// and K-swizzle as r9 (absmax 0.0 there).
// ---------------------------------------------------------------------------

typedef _Float16 f16;
typedef f16 f16x8 __attribute__((ext_vector_type(8)));
typedef float f32x4 __attribute__((ext_vector_type(4)));

#define F16_MIN_NORM 6.104e-5f

__device__ __forceinline__ void split_f16(float v, f16& h, f16& l) {
  f16 h0 = (fabsf(v) < F16_MIN_NORM) ? (f16)0.0f : (f16)v;
  float r = (v - (float)h0) * 4096.0f;
  h = h0; l = (f16)r;
}

__device__ __forceinline__ float sigm(float x) { return 1.0f / (1.0f + expf(-x)); }

#define GLOAD_LDS16(gsrc, ldst)                                               \
  __builtin_amdgcn_global_load_lds(                                           \
      (const __attribute__((address_space(1))) unsigned int*)(const void*)(gsrc), \
      (__attribute__((address_space(3))) unsigned int*)(void*)(ldst), 16, 0, 0)

// --------------------------- threefry / gumbel -----------------------------

__device__ __forceinline__ unsigned tf_rotl(unsigned x, int r) {
  return (x << r) | (x >> (32 - r));
}

// JAX threefry2x32-20, key (0,42), partitionable: draw = x0_out ^ x1_out.
__device__ inline float gumbel_at(unsigned idx) {
  const unsigned ks0 = 0u;
  const unsigned ks1 = 42u;
  const unsigned ks2 = 0x1BD11BDAu ^ ks0 ^ ks1;
  unsigned x0 = 0u + ks0;
  unsigned x1 = idx + ks1;
#define TFR(rot) { x0 += x1; x1 = tf_rotl(x1, rot); x1 ^= x0; }
  TFR(13) TFR(15) TFR(26) TFR(6)
  x0 += ks1; x1 += ks2 + 1u;
  TFR(17) TFR(29) TFR(16) TFR(24)
  x0 += ks2; x1 += ks0 + 2u;
  TFR(13) TFR(15) TFR(26) TFR(6)
  x0 += ks0; x1 += ks1 + 3u;
  TFR(17) TFR(29) TFR(16) TFR(24)
  x0 += ks1; x1 += ks2 + 4u;
  TFR(13) TFR(15) TFR(26) TFR(6)
  x0 += ks2; x1 += ks0 + 5u;
#undef TFR
  const unsigned bits = x0 ^ x1;
  const float f = __uint_as_float((bits >> 9) | 0x3F800000u) - 1.0f;
  const float tiny = 1.17549435082228751e-38f;
  const float u = fmaxf(tiny, f * (1.0f - tiny) + tiny);
  return -logf(-logf(u));
}

// ------------------------- setup / pack kernels ----------------------------

__global__ void init_kernel(float* __restrict__ out, const int* __restrict__ startp,
                            int* __restrict__ tok, int Tp1, int V) {
  const int b = blockIdx.x;
  const int start = *startp;
  if (threadIdx.x == 0) tok[b] = start;
  float* orow = out + (size_t)b * Tp1 * V;
  const int tq = start >> 2;
  for (int v4 = threadIdx.x; v4 < V / 4; v4 += blockDim.x) {
    float4 v = make_float4(0.f, 0.f, 0.f, 0.f);
    if (v4 == tq) ((float*)&v)[start & 3] = 1.0f;
    ((float4*)orow)[v4] = v;
  }
}

// packed gate col p: gate q=(p>>4)&3, unit u=((p>>6)<<4)+(p&15); orig row
// n' = q*H + u. wpk[p][k] = k<E ? wih[n'][k] : whh[n'][k-E], split.
__global__ void pack_gates_kernel(const float* __restrict__ wih,
                                  const float* __restrict__ whh,
                                  f16* __restrict__ w0, f16* __restrict__ w1,
                                  int E, int H, int K) {
  const int k = blockIdx.x * blockDim.x + threadIdx.x;
  const int p = blockIdx.y;
  if (k >= K) return;
  const int n = ((p >> 4) & 3) * H + ((p >> 6) << 4) + (p & 15);
  const float v = (k < E) ? wih[(size_t)n * E + k] : whh[(size_t)n * H + (k - E)];
  f16 h, l; split_f16(v, h, l);
  w0[(size_t)p * K + k] = h;
  w1[(size_t)p * K + k] = l;
}

__global__ void pack_bias_kernel(const float* __restrict__ bih,
                                 const float* __restrict__ bhh,
                                 float* __restrict__ bi, float* __restrict__ bh, int H) {
  const int p = blockIdx.x * blockDim.x + threadIdx.x;
  const int n = ((p >> 4) & 3) * H + ((p >> 6) << 4) + (p & 15);
  bi[p] = bih[n];
  bh[p] = bhh[n];
}

__global__ void split_kernel(const float* __restrict__ in,
                             f16* __restrict__ o0, f16* __restrict__ o1, int n) {
  const int i = blockIdx.x * blockDim.x + threadIdx.x;
  if (i < n) { f16 h, l; split_f16(in[i], h, l); o0[i] = h; o1[i] = l; }
}

// ----------------------- shared K-loop building block ----------------------
// block 256 thr / 4 waves, tile 128x64, BK=32, TRIPLE-buffered LDS (72 KB).
// Staging: 24 1KB chunks (A-hi 8, A-lo 8, B-hi 4, B-lo 4), 6 per wave.
// Wave w computes rows [w*32, w*32+32) x all 64 cols.
// Swizzle: LDS[row][slot] holds global 16B-slot (slot ^ ((row>>1)&3)).
//   stage source slot = (lane&3) ^ ((lane>>3)&3)   (srow = lane>>2)
//   read slot         = (lane>>4) ^ ((lane>>1)&3)  (row & 15 == lane & 15)

__device__ __forceinline__ void stage_chunk(
    int chunk, int srow, int scol,
    const f16* __restrict__ a0s, const f16* __restrict__ a1s, int lda, int ka, int bm,
    const f16* __restrict__ b0s, const f16* __restrict__ b1s, int ldb, int kb, int bn,
    f16 (*ldsA0)[32], f16 (*ldsA1)[32], f16 (*ldsB0)[32], f16 (*ldsB1)[32])
{
  if (chunk < 8) {
    GLOAD_LDS16(a0s + (size_t)(bm + chunk * 16 + srow) * lda + ka + scol,
                &ldsA0[chunk * 16][0]);
  } else if (chunk < 16) {
    const int s = chunk - 8;
    GLOAD_LDS16(a1s + (size_t)(bm + s * 16 + srow) * lda + ka + scol,
                &ldsA1[s * 16][0]);
  } else if (chunk < 20) {
    const int s = chunk - 16;
    GLOAD_LDS16(b0s + (size_t)(bn + s * 16 + srow) * ldb + kb + scol,
                &ldsB0[s * 16][0]);
  } else {
    const int s = chunk - 20;
    GLOAD_LDS16(b1s + (size_t)(bn + s * 16 + srow) * ldb + kb + scol,
                &ldsB1[s * 16][0]);
  }
}

#define MFMA_DECLS                                                            \
  const int tid  = threadIdx.x;                                               \
  const int lane = tid & 63;                                                  \
  const int wid  = tid >> 6;                                                  \
  const int bm   = blockIdx.y * 128;                                          \
  const int bn   = blockIdx.x * 64;                                           \
  const int wm   = wid * 32;                                                  \
  const int fr   = lane & 15;                                                 \
  const int fk   = (((lane >> 4) ^ ((lane >> 1) & 3)) * 8);                   \
  const int srow = lane >> 2;                                                 \
  const int scol = (((lane & 3) ^ ((lane >> 3) & 3)) * 8);                    \
  f32x4 acc0[2][4], acc1[2][4];                                               \
  _Pragma("unroll") for (int i = 0; i < 2; ++i)                               \
  _Pragma("unroll") for (int j = 0; j < 4; ++j) {                             \
    acc0[i][j] = (f32x4)0.0f; acc1[i][j] = (f32x4)0.0f; }

#define MFMA_LDS_DECL                                                         \
  __shared__ f16 ldsA0[3][128][32], ldsA1[3][128][32],                        \
                 ldsB0[3][64][32],  ldsB1[3][64][32];

// Issue-only staging into buffer `buf` (no barriers here).
#define MFMA_STAGE_TO(buf, a0s, a1s, lda, ka, b0s, b1s, ldb, kb)              \
  { _Pragma("unroll") for (int c = 0; c < 6; ++c)                             \
      stage_chunk(wid * 6 + c, srow, scol, (a0s), (a1s), (lda), (ka), bm,     \
                  (b0s), (b1s), (ldb), (kb), bn,                              \
                  ldsA0[(buf)], ldsA1[(buf)], ldsB0[(buf)], ldsB1[(buf)]); }

#define MFMA_COMPUTE_FROM(buf)                                                \
  {                                                                           \
    f16x8 a0[2], a1[2], b0[4], b1[4];                                         \
    _Pragma("unroll") for (int i = 0; i < 2; ++i) {                           \
      a0[i] = *(const f16x8*)&ldsA0[(buf)][wm + i * 16 + fr][fk];             \
      a1[i] = *(const f16x8*)&ldsA1[(buf)][wm + i * 16 + fr][fk];             \
    }                                                                         \
    _Pragma("unroll") for (int j = 0; j < 4; ++j) {                           \
      b0[j] = *(const f16x8*)&ldsB0[(buf)][j * 16 + fr][fk];                  \
      b1[j] = *(const f16x8*)&ldsB1[(buf)][j * 16 + fr][fk];                  \
    }                                                                         \
    _Pragma("unroll") for (int i = 0; i < 2; ++i)                             \
    _Pragma("unroll") for (int j = 0; j < 4; ++j) {                           \
      acc0[i][j] = __builtin_amdgcn_mfma_f32_16x16x32_f16(a0[i], b0[j], acc0[i][j], 0, 0, 0); \
      acc1[i][j] = __builtin_amdgcn_mfma_f32_16x16x32_f16(a0[i], b1[j], acc1[i][j], 0, 0, 0); \
      acc1[i][j] = __builtin_amdgcn_mfma_f32_16x16x32_f16(a1[i], b0[j], acc1[i][j], 0, 0, 0); \
    }                                                                         \
  }

// Triple-buffered pipeline. STAGE_T(buf, t) must be #defined per kernel.
// Steady state: 12 loads (2 stages) in flight across barriers; vmcnt never
// drains to 0 until the tail. Fences pin memory-op issue order around the
// raw barriers (hoist/sink of global_load_lds or ds_read across a raw
// s_barrier would break the counted-wait accounting).
#define PIPE(NT)                                                              \
  STAGE_T(0, 0)                                                               \
  STAGE_T(1, 1)                                                               \
  for (int t = 0; t < (NT); ++t) {                                            \
    asm volatile("" ::: "memory");                                            \
    if (t + 2 < (NT)) { STAGE_T(((t + 2) % 3), (t + 2)) }                     \
    const int rem = (NT) - 1 - t;                                             \
    if (rem >= 2)      asm volatile("s_waitcnt vmcnt(12)" ::: "memory");      \
    else if (rem == 1) asm volatile("s_waitcnt vmcnt(6)" ::: "memory");       \
    else               asm volatile("s_waitcnt vmcnt(0)" ::: "memory");       \
    __builtin_amdgcn_s_barrier();                                             \
    asm volatile("" ::: "memory");                                            \
    __builtin_amdgcn_s_setprio(1);                                            \
    MFMA_COMPUTE_FROM((t % 3))                                                \
    __builtin_amdgcn_s_setprio(0);                                            \
    asm volatile("" ::: "memory");                                            \
    __builtin_amdgcn_s_barrier();                                             \
  }

// ------------------- h0 GEMM: h0 = t @ aff_w^T + aff_b ---------------------
__global__ __launch_bounds__(256, 2) void h0_kernel(
    const f16* __restrict__ t0, const f16* __restrict__ t1, int F,
    const f16* __restrict__ aw0, const f16* __restrict__ aw1,
    const float* __restrict__ affb,
    f16* __restrict__ h0p, f16* __restrict__ h1p, int H,
    float* __restrict__ czero)
{
  MFMA_LDS_DECL
  MFMA_DECLS
  const int NT = F / 32;
#define STAGE_T(buf, t) MFMA_STAGE_TO(buf, t0, t1, F, (t) * 32, aw0, aw1, F, (t) * 32)
  PIPE(NT)
#undef STAGE_T
  const int q4 = (lane >> 4) * 4;
  const float s12 = 1.0f / 4096.0f;
#pragma unroll
  for (int j = 0; j < 4; ++j) {
    const int col = bn + j * 16 + fr;
    const float bb = affb[col];
#pragma unroll
    for (int i = 0; i < 2; ++i) {
#pragma unroll
      for (int r = 0; r < 4; ++r) {
        const int row = bm + wm + i * 16 + q4 + r;
        const float v = (acc0[i][j][r] + acc1[i][j][r] * s12) + bb;
        f16 hh, hl; split_f16(v, hh, hl);
        const size_t off = (size_t)row * H + col;
        h0p[off] = hh; h1p[off] = hl;
        czero[off] = 0.0f;
      }
    }
  }
}

// ------- gih table GEMM: gih[v][p] = emb[v].wih[n(p)] + bih + bhh ----------
__global__ __launch_bounds__(256, 2) void gih_kernel(
    const f16* __restrict__ e0, const f16* __restrict__ e1, int E,
    const f16* __restrict__ w0, const f16* __restrict__ w1, int K,
    const float* __restrict__ bi, const float* __restrict__ bh,
    float* __restrict__ gih, int NP)
{
  MFMA_LDS_DECL
  MFMA_DECLS
  const int NT = E / 32;
#define STAGE_T(buf, t) MFMA_STAGE_TO(buf, e0, e1, E, (t) * 32, w0, w1, K, (t) * 32)
  PIPE(NT)
#undef STAGE_T
  const int q4 = (lane >> 4) * 4;
  const float s12 = 1.0f / 4096.0f;
#pragma unroll
  for (int j = 0; j < 4; ++j) {
    const int col = bn + j * 16 + fr;
    const float bb = bi[col] + bh[col];
#pragma unroll
    for (int i = 0; i < 2; ++i)
#pragma unroll
      for (int r = 0; r < 4; ++r) {
        const int row = bm + wm + i * 16 + q4 + r;
        gih[(size_t)row * NP + col] = (acc0[i][j][r] + acc1[i][j][r] * s12) + bb;
      }
  }
}

// ---------------- gates GEMM + fused LSTM cell epilogue --------------------
// gates = h @ w_hh^T (K=H) + gih[tok[row]] (embedding term + both biases).
__global__ __launch_bounds__(256, 2) void gates_kernel(
    const f16* __restrict__ hin0, const f16* __restrict__ hin1, int H,
    const f16* __restrict__ w0, const f16* __restrict__ w1, int K, int E,
    const float* __restrict__ gih, int NP, const int* __restrict__ tok,
    float* __restrict__ cbuf,
    f16* __restrict__ hout0, f16* __restrict__ hout1)
{
  MFMA_LDS_DECL
  MFMA_DECLS
  const int NT = H / 32;
#define STAGE_T(buf, t) MFMA_STAGE_TO(buf, hin0, hin1, H, (t) * 32, w0, w1, K, E + (t) * 32)
  PIPE(NT)
#undef STAGE_T
  // epilogue: packed cols -> unit u = (bn>>2)+fr, gate q = j.
  const int q4 = (lane >> 4) * 4;
  const float s12 = 1.0f / 4096.0f;
  const int nunit = (bn >> 2) + fr;
#pragma unroll
  for (int i = 0; i < 2; ++i) {
#pragma unroll
    for (int r = 0; r < 4; ++r) {
      const int row = bm + wm + i * 16 + q4 + r;
      const float* gr = gih + (size_t)tok[row] * NP + bn + fr;
      float gv[4];
#pragma unroll
      for (int j = 0; j < 4; ++j)
        gv[j] = (acc0[i][j][r] + acc1[i][j][r] * s12) + gr[j * 16];
      const size_t off = (size_t)row * H + nunit;
      const float c = cbuf[off];
      const float cn = __fadd_rn(__fmul_rn(sigm(gv[1]), c),
                                 __fmul_rn(sigm(gv[0]), tanhf(gv[2])));
      const float hn = __fmul_rn(sigm(gv[3]), tanhf(cn));
      cbuf[off] = cn;
      f16 hh, hl; split_f16(hn, hh, hl);
      hout0[off] = hh; hout1[off] = hl;
    }
  }
}

// ------------- logits GEMM + fused argmax-partials epilogue ----------------
__global__ __launch_bounds__(256, 2) void logits_kernel(
    const f16* __restrict__ h0p, const f16* __restrict__ h1p, int H,
    const f16* __restrict__ w0, const f16* __restrict__ w1,
    const float* __restrict__ lpb,
    float* __restrict__ partM, int* __restrict__ partI,
    int step, int B, int V)
{
  MFMA_LDS_DECL
  MFMA_DECLS
  const int NT = H / 32;
#define STAGE_T(buf, t) MFMA_STAGE_TO(buf, h0p, h1p, H, (t) * 32, w0, w1, H, (t) * 32)
  PIPE(NT)
#undef STAGE_T
  const int q4 = (lane >> 4) * 4;
  const float s12 = 1.0f / 4096.0f;
  float bv[4];
#pragma unroll
  for (int j = 0; j < 4; ++j) bv[j] = lpb[bn + j * 16 + fr];
  // w = logit + gumbel, overwrite acc0
#pragma unroll
  for (int i = 0; i < 2; ++i)
#pragma unroll
    for (int j = 0; j < 4; ++j) {
      const int col = bn + j * 16 + fr;
#pragma unroll
      for (int r = 0; r < 4; ++r) {
        const int row = bm + wm + i * 16 + q4 + r;
        const float logit = (acc0[i][j][r] + acc1[i][j][r] * s12) + bv[j];
        const unsigned gidx = ((unsigned)(step * B + row)) * (unsigned)V + (unsigned)col;
        acc0[i][j][r] = logit + gumbel_at(gidx);
      }
    }
  // per-row argmax over this block's 64 cols (within each 16-lane group).
  // sc == 1.0 exactly, so no denominator partials needed.
  const int grp = bn >> 6;   // == blockIdx.x
#pragma unroll
  for (int i = 0; i < 2; ++i) {
#pragma unroll
    for (int r = 0; r < 4; ++r) {
      float mx = -INFINITY; int ix = 0;
#pragma unroll
      for (int j = 0; j < 4; ++j) {
        const float w = acc0[i][j][r];
        const int col = bn + j * 16 + fr;
        if (w > mx) { mx = w; ix = col; }
      }
#pragma unroll
      for (int m = 1; m < 16; m <<= 1) {
        const float om = __shfl_xor(mx, m, 64);
        const int oi = __shfl_xor(ix, m, 64);
        if (om > mx || (om == mx && oi < ix)) { mx = om; ix = oi; }
      }
      if (fr == 0) {
        const int row = bm + wm + i * 16 + q4 + r;
        partM[(size_t)row * 64 + grp] = mx;
        partI[(size_t)row * 64 + grp] = ix;
      }
    }
  }
}

// ----------- finalize: argmax reduce, write one-hot, publish tok -----------
__global__ __launch_bounds__(256) void finalize_kernel(
    const float* __restrict__ partM, const int* __restrict__ partI,
    float* __restrict__ out, int* __restrict__ tok,
    int step, int Tp1, int V)
{
  const int b = blockIdx.x;
  const int tid = threadIdx.x;
  __shared__ int s_tok;

  if (tid < 64) {
    float mx = partM[(size_t)b * 64 + tid];
    int ix = partI[(size_t)b * 64 + tid];
#pragma unroll
    for (int m = 1; m < 64; m <<= 1) {
      const float om = __shfl_xor(mx, m, 64);
      const int oi = __shfl_xor(ix, m, 64);
      if (om > mx || (om == mx && oi < ix)) { mx = om; ix = oi; }
    }
    if (tid == 0) { s_tok = ix; tok[b] = ix; }
  }
  __syncthreads();
  const int tk = s_tok;

  // one-hot write with exact 1.0 (sc == (1-y)+y == 1.0f identically)
  float* orow = out + ((size_t)b * Tp1 + step + 1) * V;
  const int tq = tk >> 2;
#pragma unroll
  for (int j = 0; j < 4; ++j) {
    const int idx = tid + 256 * j;
    float4 v = make_float4(0.f, 0.f, 0.f, 0.f);
    if (idx == tq) ((float*)&v)[tk & 3] = 1.0f;
    ((float4*)orow)[idx] = v;
  }
}

// ------------------------------- host side ---------------------------------

extern "C" void kernel_launch(void* const* d_in, const int* in_sizes, int n_in,
                              void* d_out, int out_size, void* d_ws, size_t ws_size,
                              hipStream_t stream) {
  const float* t     = (const float*)d_in[0];
  const float* emb   = (const float*)d_in[1];
  const float* affw  = (const float*)d_in[2];
  const float* affb  = (const float*)d_in[3];
  const float* wih   = (const float*)d_in[4];
  const float* whh   = (const float*)d_in[5];
  const float* bih   = (const float*)d_in[6];
  const float* bhh   = (const float*)d_in[7];
  const float* lpw   = (const float*)d_in[8];
  const float* lpb   = (const float*)d_in[9];
  const int*   start = (const int*)d_in[10];
  float* out = (float*)d_out;

  const int H = in_sizes[3];             // 1024
  const int V = in_sizes[9];             // 4096
  const int E = in_sizes[1] / V;         // 256
  const int F = in_sizes[2] / H;         // 2048
  const int B = in_sizes[0] / F;         // 1024
  const int Tp1 = out_size / (B * V);    // 33
  const int T = Tp1 - 1;                 // 32
  const int KG = E + H;                  // 1280
  const int NP = 4 * H;                  // 4096 packed gate cols

  // ---- workspace layout (~190 MB) ----
  char* p = (char*)d_ws;
  float* gihb  = (float*)p; p += (size_t)V * NP * 4;          // 64 MB gih table
  float* cbuf  = (float*)p; p += (size_t)B * H * 4;           // 4 MB
  f16* hA0[2]; f16* hA1[2];
  hA0[0] = (f16*)p; p += (size_t)B * H * 2;
  hA1[0] = (f16*)p; p += (size_t)B * H * 2;
  hA0[1] = (f16*)p; p += (size_t)B * H * 2;
  hA1[1] = (f16*)p; p += (size_t)B * H * 2;                   // 8 MB
  f16* wg0 = (f16*)p; p += (size_t)V * KG * 2;                // 21 MB packed gates
  f16* wg1 = (f16*)p; p += (size_t)V * KG * 2;
  f16* wl0 = (f16*)p; p += (size_t)V * H * 2;                 // 16 MB lp_w
  f16* wl1 = (f16*)p; p += (size_t)V * H * 2;
  f16* t0  = (f16*)p; p += (size_t)B * F * 2;                 // 8 MB t planes
  f16* t1  = (f16*)p; p += (size_t)B * F * 2;
  f16* aw0 = (f16*)p; p += (size_t)H * F * 2;                 // 8 MB aff_w planes
  f16* aw1 = (f16*)p; p += (size_t)H * F * 2;
  f16* em0 = (f16*)p; p += (size_t)V * E * 2;                 // 4 MB emb planes
  f16* em1 = (f16*)p; p += (size_t)V * E * 2;
  float* bgi = (float*)p; p += (size_t)NP * 4;
  float* bgh = (float*)p; p += (size_t)NP * 4;
  float* partM = (float*)p; p += (size_t)B * 64 * 4;
  int*   partI = (int*)p;   p += (size_t)B * 64 * 4;
  int*   tokb  = (int*)p;   p += (size_t)B * 4;
  (void)ws_size; (void)n_in;

  // ---- setup ----
  init_kernel<<<B, 256, 0, stream>>>(out, start, tokb, Tp1, V);
  pack_gates_kernel<<<dim3((KG + 255) / 256, NP), 256, 0, stream>>>(
      wih, whh, wg0, wg1, E, H, KG);
  pack_bias_kernel<<<NP / 256, 256, 0, stream>>>(bih, bhh, bgi, bgh, H);
  split_kernel<<<(V * H + 255) / 256, 256, 0, stream>>>(lpw, wl0, wl1, V * H);
  split_kernel<<<(B * F + 255) / 256, 256, 0, stream>>>(t, t0, t1, B * F);
  split_kernel<<<(H * F + 255) / 256, 256, 0, stream>>>(affw, aw0, aw1, H * F);
  split_kernel<<<(V * E + 255) / 256, 256, 0, stream>>>(emb, em0, em1, V * E);
  // h0 = t @ aff_w^T + aff_b -> split into hA[0]; zero cbuf
  h0_kernel<<<dim3(H / 64, B / 128), 256, 0, stream>>>(
      t0, t1, F, aw0, aw1, affb, hA0[0], hA1[0], H, cbuf);
  // gih = emb @ w_ih^T + b_ih + b_hh (packed cols), f32
  gih_kernel<<<dim3(NP / 64, V / 128), 256, 0, stream>>>(
      em0, em1, E, wg0, wg1, KG, bgi, bgh, gihb, NP);

  for (int s = 0; s < T; ++s) {
    const int cur = s & 1, nxt = (s + 1) & 1;
    gates_kernel<<<dim3(NP / 64, B / 128), 256, 0, stream>>>(
        hA0[cur], hA1[cur], H, wg0, wg1, KG, E, gihb, NP, tokb,
        cbuf, hA0[nxt], hA1[nxt]);
    logits_kernel<<<dim3(V / 64, B / 128), 256, 0, stream>>>(
        hA0[nxt], hA1[nxt], H, wl0, wl1, lpb,
        partM, partI, s, B, V);
    finalize_kernel<<<B, 256, 0, stream>>>(
        partM, partI, out, tokb, s, Tp1, V);
  }
}

// Round 3
// 3954.147 us; speedup vs baseline: 1.3087x; 1.0034x over previous
//
#include <hip/hip_runtime.h>
#include <math.h>

// ---------------------------------------------------------------------------
// Sender: LSTM + Gumbel straight-through decode, 32 steps.
// Round 11 (from r10, 3968 us):
//  (1) Tile 128x64 -> 128x128, 512 thr / 8 waves (wave = 32x64 sub-tile,
//      wr=wid&3 row-quarter, wc=wid>>2 col-half). Per-GEMM global->LDS
//      staging traffic 393 MB -> 256 MB (-35%); traffic per MFMA halves.
//      Grid 256 blocks = exactly 1 block/CU, zero tail. Same per-wave
//      fragment shape, ds_read count, and swizzle constants as r10 (the
//      XOR swizzle algebra depends only on `lane`; rows stay 16-aligned).
//  (2) 4-deep LDS pipeline (4 x 32 KB = 128 KB static LDS, m201 precedent):
//      stage tile t+3 before the pre-compute barrier; counted waits
//      vmcnt(12)/8/4/0 (4 chunk-loads per wave per stage; wait for stage t
//      = allow 3 newer stages in flight). ~3 compute phases (~2800 cyc) of
//      latency cover vs ~900 cyc HBM-miss.
//  (3) Default XCD round-robin (id%8 = x%8 since gridDim.x%8==0) already
//      co-locates the 8 blocks sharing each weight panel on one XCD ->
//      weight panels fetched ~once per XCD from L3.
// MFMA math: f16 2-way split (3 MFMA/product), identical products and
// accumulation order to r10 (absmax 0.0 there); only block geometry moved.
// ---------------------------------------------------------------------------

typedef _Float16 f16;
typedef f16 f16x8 __attribute__((ext_vector_type(8)));
typedef float f32x4 __attribute__((ext_vector_type(4)));

#define F16_MIN_NORM 6.104e-5f

__device__ __forceinline__ void split_f16(float v, f16& h, f16& l) {
  f16 h0 = (fabsf(v) < F16_MIN_NORM) ? (f16)0.0f : (f16)v;
  float r = (v - (float)h0) * 4096.0f;
  h = h0; l = (f16)r;
}

__device__ __forceinline__ float sigm(float x) { return 1.0f / (1.0f + expf(-x)); }

#define GLOAD_LDS16(gsrc, ldst)                                               \
  __builtin_amdgcn_global_load_lds(                                           \
      (const __attribute__((address_space(1))) unsigned int*)(const void*)(gsrc), \
      (__attribute__((address_space(3))) unsigned int*)(void*)(ldst), 16, 0, 0)

// --------------------------- threefry / gumbel -----------------------------

__device__ __forceinline__ unsigned tf_rotl(unsigned x, int r) {
  return (x << r) | (x >> (32 - r));
}

// JAX threefry2x32-20, key (0,42), partitionable: draw = x0_out ^ x1_out.
__device__ inline float gumbel_at(unsigned idx) {
  const unsigned ks0 = 0u;
  const unsigned ks1 = 42u;
  const unsigned ks2 = 0x1BD11BDAu ^ ks0 ^ ks1;
  unsigned x0 = 0u + ks0;
  unsigned x1 = idx + ks1;
#define TFR(rot) { x0 += x1; x1 = tf_rotl(x1, rot); x1 ^= x0; }
  TFR(13) TFR(15) TFR(26) TFR(6)
  x0 += ks1; x1 += ks2 + 1u;
  TFR(17) TFR(29) TFR(16) TFR(24)
  x0 += ks2; x1 += ks0 + 2u;
  TFR(13) TFR(15) TFR(26) TFR(6)
  x0 += ks0; x1 += ks1 + 3u;
  TFR(17) TFR(29) TFR(16) TFR(24)
  x0 += ks1; x1 += ks2 + 4u;
  TFR(13) TFR(15) TFR(26) TFR(6)
  x0 += ks2; x1 += ks0 + 5u;
#undef TFR
  const unsigned bits = x0 ^ x1;
  const float f = __uint_as_float((bits >> 9) | 0x3F800000u) - 1.0f;
  const float tiny = 1.17549435082228751e-38f;
  const float u = fmaxf(tiny, f * (1.0f - tiny) + tiny);
  return -logf(-logf(u));
}

// ------------------------- setup / pack kernels ----------------------------

__global__ void init_kernel(float* __restrict__ out, const int* __restrict__ startp,
                            int* __restrict__ tok, int Tp1, int V) {
  const int b = blockIdx.x;
  const int start = *startp;
  if (threadIdx.x == 0) tok[b] = start;
  float* orow = out + (size_t)b * Tp1 * V;
  const int tq = start >> 2;
  for (int v4 = threadIdx.x; v4 < V / 4; v4 += blockDim.x) {
    float4 v = make_float4(0.f, 0.f, 0.f, 0.f);
    if (v4 == tq) ((float*)&v)[start & 3] = 1.0f;
    ((float4*)orow)[v4] = v;
  }
}

// packed gate col p: gate q=(p>>4)&3, unit u=((p>>6)<<4)+(p&15); orig row
// n' = q*H + u. wpk[p][k] = k<E ? wih[n'][k] : whh[n'][k-E], split.
__global__ void pack_gates_kernel(const float* __restrict__ wih,
                                  const float* __restrict__ whh,
                                  f16* __restrict__ w0, f16* __restrict__ w1,
                                  int E, int H, int K) {
  const int k = blockIdx.x * blockDim.x + threadIdx.x;
  const int p = blockIdx.y;
  if (k >= K) return;
  const int n = ((p >> 4) & 3) * H + ((p >> 6) << 4) + (p & 15);
  const float v = (k < E) ? wih[(size_t)n * E + k] : whh[(size_t)n * H + (k - E)];
  f16 h, l; split_f16(v, h, l);
  w0[(size_t)p * K + k] = h;
  w1[(size_t)p * K + k] = l;
}

__global__ void pack_bias_kernel(const float* __restrict__ bih,
                                 const float* __restrict__ bhh,
                                 float* __restrict__ bi, float* __restrict__ bh, int H) {
  const int p = blockIdx.x * blockDim.x + threadIdx.x;
  const int n = ((p >> 4) & 3) * H + ((p >> 6) << 4) + (p & 15);
  bi[p] = bih[n];
  bh[p] = bhh[n];
}

__global__ void split_kernel(const float* __restrict__ in,
                             f16* __restrict__ o0, f16* __restrict__ o1, int n) {
  const int i = blockIdx.x * blockDim.x + threadIdx.x;
  if (i < n) { f16 h, l; split_f16(in[i], h, l); o0[i] = h; o1[i] = l; }
}

// ----------------------- shared K-loop building block ----------------------
// block 512 thr / 8 waves, tile 128x128, BK=32, 4-deep LDS pipeline (128 KB).
// Staging: 32 1KB chunks (A-hi 8, A-lo 8, B-hi 8, B-lo 8), 4 per wave.
// Wave (wr=wid&3, wc=wid>>2) computes rows [wr*32,+32) x cols [wc*64,+64).
// Swizzle: LDS[row][slot] holds global 16B-slot (slot ^ ((row>>1)&3)).
//   stage source slot = (lane&3) ^ ((lane>>3)&3)   (srow = lane>>2)
//   read slot         = (lane>>4) ^ ((lane>>1)&3)  (row & 15 == lane & 15)

__device__ __forceinline__ void stage_chunk(
    int chunk, int srow, int scol,
    const f16* __restrict__ a0s, const f16* __restrict__ a1s, int lda, int ka, int bm,
    const f16* __restrict__ b0s, const f16* __restrict__ b1s, int ldb, int kb, int bn,
    f16 (*ldsA0)[32], f16 (*ldsA1)[32], f16 (*ldsB0)[32], f16 (*ldsB1)[32])
{
  if (chunk < 8) {
    GLOAD_LDS16(a0s + (size_t)(bm + chunk * 16 + srow) * lda + ka + scol,
                &ldsA0[chunk * 16][0]);
  } else if (chunk < 16) {
    const int s = chunk - 8;
    GLOAD_LDS16(a1s + (size_t)(bm + s * 16 + srow) * lda + ka + scol,
                &ldsA1[s * 16][0]);
  } else if (chunk < 24) {
    const int s = chunk - 16;
    GLOAD_LDS16(b0s + (size_t)(bn + s * 16 + srow) * ldb + kb + scol,
                &ldsB0[s * 16][0]);
  } else {
    const int s = chunk - 24;
    GLOAD_LDS16(b1s + (size_t)(bn + s * 16 + srow) * ldb + kb + scol,
                &ldsB1[s * 16][0]);
  }
}

#define MFMA_DECLS                                                            \
  const int tid  = threadIdx.x;                                               \
  const int lane = tid & 63;                                                  \
  const int wid  = tid >> 6;                                                  \
  const int bm   = blockIdx.y * 128;                                          \
  const int bn   = blockIdx.x * 128;                                          \
  const int wm   = (wid & 3) * 32;                                            \
  const int wn   = (wid >> 2) * 64;                                           \
  const int fr   = lane & 15;                                                 \
  const int fk   = (((lane >> 4) ^ ((lane >> 1) & 3)) * 8);                   \
  const int srow = lane >> 2;                                                 \
  const int scol = (((lane & 3) ^ ((lane >> 3) & 3)) * 8);                    \
  f32x4 acc0[2][4], acc1[2][4];                                               \
  _Pragma("unroll") for (int i = 0; i < 2; ++i)                               \
  _Pragma("unroll") for (int j = 0; j < 4; ++j) {                             \
    acc0[i][j] = (f32x4)0.0f; acc1[i][j] = (f32x4)0.0f; }

#define MFMA_LDS_DECL                                                         \
  __shared__ f16 ldsA0[4][128][32], ldsA1[4][128][32],                        \
                 ldsB0[4][128][32], ldsB1[4][128][32];

// Issue-only staging into buffer `buf` (no barriers here).
#define MFMA_STAGE_TO(buf, a0s, a1s, lda, ka, b0s, b1s, ldb, kb)              \
  { _Pragma("unroll") for (int c = 0; c < 4; ++c)                             \
      stage_chunk(wid * 4 + c, srow, scol, (a0s), (a1s), (lda), (ka), bm,     \
                  (b0s), (b1s), (ldb), (kb), bn,                              \
                  ldsA0[(buf)], ldsA1[(buf)], ldsB0[(buf)], ldsB1[(buf)]); }

#define MFMA_COMPUTE_FROM(buf)                                                \
  {                                                                           \
    f16x8 a0[2], a1[2], b0[4], b1[4];                                         \
    _Pragma("unroll") for (int i = 0; i < 2; ++i) {                           \
      a0[i] = *(const f16x8*)&ldsA0[(buf)][wm + i * 16 + fr][fk];             \
      a1[i] = *(const f16x8*)&ldsA1[(buf)][wm + i * 16 + fr][fk];             \
    }                                                                         \
    _Pragma("unroll") for (int j = 0; j < 4; ++j) {                           \
      b0[j] = *(const f16x8*)&ldsB0[(buf)][wn + j * 16 + fr][fk];             \
      b1[j] = *(const f16x8*)&ldsB1[(buf)][wn + j * 16 + fr][fk];             \
    }                                                                         \
    _Pragma("unroll") for (int i = 0; i < 2; ++i)                             \
    _Pragma("unroll") for (int j = 0; j < 4; ++j) {                           \
      acc0[i][j] = __builtin_amdgcn_mfma_f32_16x16x32_f16(a0[i], b0[j], acc0[i][j], 0, 0, 0); \
      acc1[i][j] = __builtin_amdgcn_mfma_f32_16x16x32_f16(a0[i], b1[j], acc1[i][j], 0, 0, 0); \
      acc1[i][j] = __builtin_amdgcn_mfma_f32_16x16x32_f16(a1[i], b0[j], acc1[i][j], 0, 0, 0); \
    }                                                                         \
  }

// 4-deep pipeline. STAGE_T(buf, t) must be #defined per kernel.
// Steady state: 3 newer stages (12 loads/wave) in flight across barriers;
// vmcnt never drains to 0 until the tail. Fences pin memory-op issue order
// around the raw barriers.
#define PIPE(NT)                                                              \
  STAGE_T(0, 0)                                                               \
  STAGE_T(1, 1)                                                               \
  STAGE_T(2, 2)                                                               \
  for (int t = 0; t < (NT); ++t) {                                            \
    asm volatile("" ::: "memory");                                            \
    if (t + 3 < (NT)) { STAGE_T(((t + 3) & 3), (t + 3)) }                     \
    const int rem = (NT) - 1 - t;                                             \
    if (rem >= 3)      asm volatile("s_waitcnt vmcnt(12)" ::: "memory");      \
    else if (rem == 2) asm volatile("s_waitcnt vmcnt(8)" ::: "memory");       \
    else if (rem == 1) asm volatile("s_waitcnt vmcnt(4)" ::: "memory");       \
    else               asm volatile("s_waitcnt vmcnt(0)" ::: "memory");       \
    __builtin_amdgcn_s_barrier();                                             \
    asm volatile("" ::: "memory");                                            \
    __builtin_amdgcn_s_setprio(1);                                            \
    MFMA_COMPUTE_FROM((t & 3))                                                \
    __builtin_amdgcn_s_setprio(0);                                            \
    asm volatile("" ::: "memory");                                            \
    __builtin_amdgcn_s_barrier();                                             \
  }

// ------------------- h0 GEMM: h0 = t @ aff_w^T + aff_b ---------------------
__global__ __launch_bounds__(512, 2) void h0_kernel(
    const f16* __restrict__ t0, const f16* __restrict__ t1, int F,
    const f16* __restrict__ aw0, const f16* __restrict__ aw1,
    const float* __restrict__ affb,
    f16* __restrict__ h0p, f16* __restrict__ h1p, int H,
    float* __restrict__ czero)
{
  MFMA_LDS_DECL
  MFMA_DECLS
  const int NT = F / 32;
#define STAGE_T(buf, t) MFMA_STAGE_TO(buf, t0, t1, F, (t) * 32, aw0, aw1, F, (t) * 32)
  PIPE(NT)
#undef STAGE_T
  const int q4 = (lane >> 4) * 4;
  const float s12 = 1.0f / 4096.0f;
  const int cn0 = bn + wn;
#pragma unroll
  for (int j = 0; j < 4; ++j) {
    const int col = cn0 + j * 16 + fr;
    const float bb = affb[col];
#pragma unroll
    for (int i = 0; i < 2; ++i) {
#pragma unroll
      for (int r = 0; r < 4; ++r) {
        const int row = bm + wm + i * 16 + q4 + r;
        const float v = (acc0[i][j][r] + acc1[i][j][r] * s12) + bb;
        f16 hh, hl; split_f16(v, hh, hl);
        const size_t off = (size_t)row * H + col;
        h0p[off] = hh; h1p[off] = hl;
        czero[off] = 0.0f;
      }
    }
  }
}

// ------- gih table GEMM: gih[v][p] = emb[v].wih[n(p)] + bih + bhh ----------
__global__ __launch_bounds__(512, 2) void gih_kernel(
    const f16* __restrict__ e0, const f16* __restrict__ e1, int E,
    const f16* __restrict__ w0, const f16* __restrict__ w1, int K,
    const float* __restrict__ bi, const float* __restrict__ bh,
    float* __restrict__ gih, int NP)
{
  MFMA_LDS_DECL
  MFMA_DECLS
  const int NT = E / 32;
#define STAGE_T(buf, t) MFMA_STAGE_TO(buf, e0, e1, E, (t) * 32, w0, w1, K, (t) * 32)
  PIPE(NT)
#undef STAGE_T
  const int q4 = (lane >> 4) * 4;
  const float s12 = 1.0f / 4096.0f;
  const int cn0 = bn + wn;
#pragma unroll
  for (int j = 0; j < 4; ++j) {
    const int col = cn0 + j * 16 + fr;
    const float bb = bi[col] + bh[col];
#pragma unroll
    for (int i = 0; i < 2; ++i)
#pragma unroll
      for (int r = 0; r < 4; ++r) {
        const int row = bm + wm + i * 16 + q4 + r;
        gih[(size_t)row * NP + col] = (acc0[i][j][r] + acc1[i][j][r] * s12) + bb;
      }
  }
}

// ---------------- gates GEMM + fused LSTM cell epilogue --------------------
// gates = h @ w_hh^T (K=H) + gih[tok[row]] (embedding term + both biases).
__global__ __launch_bounds__(512, 2) void gates_kernel(
    const f16* __restrict__ hin0, const f16* __restrict__ hin1, int H,
    const f16* __restrict__ w0, const f16* __restrict__ w1, int K, int E,
    const float* __restrict__ gih, int NP, const int* __restrict__ tok,
    float* __restrict__ cbuf,
    f16* __restrict__ hout0, f16* __restrict__ hout1)
{
  MFMA_LDS_DECL
  MFMA_DECLS
  const int NT = H / 32;
#define STAGE_T(buf, t) MFMA_STAGE_TO(buf, hin0, hin1, H, (t) * 32, w0, w1, K, E + (t) * 32)
  PIPE(NT)
#undef STAGE_T
  // epilogue: packed cols -> unit u = (cn0>>2)+fr, gate q = j.
  const int q4 = (lane >> 4) * 4;
  const float s12 = 1.0f / 4096.0f;
  const int cn0 = bn + wn;
  const int nunit = (cn0 >> 2) + fr;
#pragma unroll
  for (int i = 0; i < 2; ++i) {
#pragma unroll
    for (int r = 0; r < 4; ++r) {
      const int row = bm + wm + i * 16 + q4 + r;
      const float* gr = gih + (size_t)tok[row] * NP + cn0 + fr;
      float gv[4];
#pragma unroll
      for (int j = 0; j < 4; ++j)
        gv[j] = (acc0[i][j][r] + acc1[i][j][r] * s12) + gr[j * 16];
      const size_t off = (size_t)row * H + nunit;
      const float c = cbuf[off];
      const float cn = __fadd_rn(__fmul_rn(sigm(gv[1]), c),
                                 __fmul_rn(sigm(gv[0]), tanhf(gv[2])));
      const float hn = __fmul_rn(sigm(gv[3]), tanhf(cn));
      cbuf[off] = cn;
      f16 hh, hl; split_f16(hn, hh, hl);
      hout0[off] = hh; hout1[off] = hl;
    }
  }
}

// ------------- logits GEMM + fused argmax-partials epilogue ----------------
__global__ __launch_bounds__(512, 2) void logits_kernel(
    const f16* __restrict__ h0p, const f16* __restrict__ h1p, int H,
    const f16* __restrict__ w0, const f16* __restrict__ w1,
    const float* __restrict__ lpb,
    float* __restrict__ partM, int* __restrict__ partI,
    int step, int B, int V)
{
  MFMA_LDS_DECL
  MFMA_DECLS
  const int NT = H / 32;
#define STAGE_T(buf, t) MFMA_STAGE_TO(buf, h0p, h1p, H, (t) * 32, w0, w1, H, (t) * 32)
  PIPE(NT)
#undef STAGE_T
  const int q4 = (lane >> 4) * 4;
  const float s12 = 1.0f / 4096.0f;
  const int cn0 = bn + wn;
  float bv[4];
#pragma unroll
  for (int j = 0; j < 4; ++j) bv[j] = lpb[cn0 + j * 16 + fr];
  // w = logit + gumbel, overwrite acc0
#pragma unroll
  for (int i = 0; i < 2; ++i)
#pragma unroll
    for (int j = 0; j < 4; ++j) {
      const int col = cn0 + j * 16 + fr;
#pragma unroll
      for (int r = 0; r < 4; ++r) {
        const int row = bm + wm + i * 16 + q4 + r;
        const float logit = (acc0[i][j][r] + acc1[i][j][r] * s12) + bv[j];
        const unsigned gidx = ((unsigned)(step * B + row)) * (unsigned)V + (unsigned)col;
        acc0[i][j][r] = logit + gumbel_at(gidx);
      }
    }
  // per-row argmax over this wave's 64 cols (within each 16-lane group).
  // sc == 1.0 exactly, so no denominator partials needed.
  const int grp = cn0 >> 6;   // 64 col-groups of 64
#pragma unroll
  for (int i = 0; i < 2; ++i) {
#pragma unroll
    for (int r = 0; r < 4; ++r) {
      float mx = -INFINITY; int ix = 0;
#pragma unroll
      for (int j = 0; j < 4; ++j) {
        const float w = acc0[i][j][r];
        const int col = cn0 + j * 16 + fr;
        if (w > mx) { mx = w; ix = col; }
      }
#pragma unroll
      for (int m = 1; m < 16; m <<= 1) {
        const float om = __shfl_xor(mx, m, 64);
        const int oi = __shfl_xor(ix, m, 64);
        if (om > mx || (om == mx && oi < ix)) { mx = om; ix = oi; }
      }
      if (fr == 0) {
        const int row = bm + wm + i * 16 + q4 + r;
        partM[(size_t)row * 64 + grp] = mx;
        partI[(size_t)row * 64 + grp] = ix;
      }
    }
  }
}

// ----------- finalize: argmax reduce, write one-hot, publish tok -----------
__global__ __launch_bounds__(256) void finalize_kernel(
    const float* __restrict__ partM, const int* __restrict__ partI,
    float* __restrict__ out, int* __restrict__ tok,
    int step, int Tp1, int V)
{
  const int b = blockIdx.x;
  const int tid = threadIdx.x;
  __shared__ int s_tok;

  if (tid < 64) {
    float mx = partM[(size_t)b * 64 + tid];
    int ix = partI[(size_t)b * 64 + tid];
#pragma unroll
    for (int m = 1; m < 64; m <<= 1) {
      const float om = __shfl_xor(mx, m, 64);
      const int oi = __shfl_xor(ix, m, 64);
      if (om > mx || (om == mx && oi < ix)) { mx = om; ix = oi; }
    }
    if (tid == 0) { s_tok = ix; tok[b] = ix; }
  }
  __syncthreads();
  const int tk = s_tok;

  // one-hot write with exact 1.0 (sc == (1-y)+y == 1.0f identically)
  float* orow = out + ((size_t)b * Tp1 + step + 1) * V;
  const int tq = tk >> 2;
#pragma unroll
  for (int j = 0; j < 4; ++j) {
    const int idx = tid + 256 * j;
    float4 v = make_float4(0.f, 0.f, 0.f, 0.f);
    if (idx == tq) ((float*)&v)[tk & 3] = 1.0f;
    ((float4*)orow)[idx] = v;
  }
}

// ------------------------------- host side ---------------------------------

extern "C" void kernel_launch(void* const* d_in, const int* in_sizes, int n_in,
                              void* d_out, int out_size, void* d_ws, size_t ws_size,
                              hipStream_t stream) {
  const float* t     = (const float*)d_in[0];
  const float* emb   = (const float*)d_in[1];
  const float* affw  = (const float*)d_in[2];
  const float* affb  = (const float*)d_in[3];
  const float* wih   = (const float*)d_in[4];
  const float* whh   = (const float*)d_in[5];
  const float* bih   = (const float*)d_in[6];
  const float* bhh   = (const float*)d_in[7];
  const float* lpw   = (const float*)d_in[8];
  const float* lpb   = (const float*)d_in[9];
  const int*   start = (const int*)d_in[10];
  float* out = (float*)d_out;

  const int H = in_sizes[3];             // 1024
  const int V = in_sizes[9];             // 4096
  const int E = in_sizes[1] / V;         // 256
  const int F = in_sizes[2] / H;         // 2048
  const int B = in_sizes[0] / F;         // 1024
  const int Tp1 = out_size / (B * V);    // 33
  const int T = Tp1 - 1;                 // 32
  const int KG = E + H;                  // 1280
  const int NP = 4 * H;                  // 4096 packed gate cols

  // ---- workspace layout (~190 MB) ----
  char* p = (char*)d_ws;
  float* gihb  = (float*)p; p += (size_t)V * NP * 4;          // 64 MB gih table
  float* cbuf  = (float*)p; p += (size_t)B * H * 4;           // 4 MB
  f16* hA0[2]; f16* hA1[2];
  hA0[0] = (f16*)p; p += (size_t)B * H * 2;
  hA1[0] = (f16*)p; p += (size_t)B * H * 2;
  hA0[1] = (f16*)p; p += (size_t)B * H * 2;
  hA1[1] = (f16*)p; p += (size_t)B * H * 2;                   // 8 MB
  f16* wg0 = (f16*)p; p += (size_t)V * KG * 2;                // 21 MB packed gates
  f16* wg1 = (f16*)p; p += (size_t)V * KG * 2;
  f16* wl0 = (f16*)p; p += (size_t)V * H * 2;                 // 16 MB lp_w
  f16* wl1 = (f16*)p; p += (size_t)V * H * 2;
  f16* t0  = (f16*)p; p += (size_t)B * F * 2;                 // 8 MB t planes
  f16* t1  = (f16*)p; p += (size_t)B * F * 2;
  f16* aw0 = (f16*)p; p += (size_t)H * F * 2;                 // 8 MB aff_w planes
  f16* aw1 = (f16*)p; p += (size_t)H * F * 2;
  f16* em0 = (f16*)p; p += (size_t)V * E * 2;                 // 4 MB emb planes
  f16* em1 = (f16*)p; p += (size_t)V * E * 2;
  float* bgi = (float*)p; p += (size_t)NP * 4;
  float* bgh = (float*)p; p += (size_t)NP * 4;
  float* partM = (float*)p; p += (size_t)B * 64 * 4;
  int*   partI = (int*)p;   p += (size_t)B * 64 * 4;
  int*   tokb  = (int*)p;   p += (size_t)B * 4;
  (void)ws_size; (void)n_in;

  // ---- setup ----
  init_kernel<<<B, 256, 0, stream>>>(out, start, tokb, Tp1, V);
  pack_gates_kernel<<<dim3((KG + 255) / 256, NP), 256, 0, stream>>>(
      wih, whh, wg0, wg1, E, H, KG);
  pack_bias_kernel<<<NP / 256, 256, 0, stream>>>(bih, bhh, bgi, bgh, H);
  split_kernel<<<(V * H + 255) / 256, 256, 0, stream>>>(lpw, wl0, wl1, V * H);
  split_kernel<<<(B * F + 255) / 256, 256, 0, stream>>>(t, t0, t1, B * F);
  split_kernel<<<(H * F + 255) / 256, 256, 0, stream>>>(affw, aw0, aw1, H * F);
  split_kernel<<<(V * E + 255) / 256, 256, 0, stream>>>(emb, em0, em1, V * E);
  // h0 = t @ aff_w^T + aff_b -> split into hA[0]; zero cbuf
  h0_kernel<<<dim3(H / 128, B / 128), 512, 0, stream>>>(
      t0, t1, F, aw0, aw1, affb, hA0[0], hA1[0], H, cbuf);
  // gih = emb @ w_ih^T + b_ih + b_hh (packed cols), f32
  gih_kernel<<<dim3(NP / 128, V / 128), 512, 0, stream>>>(
      em0, em1, E, wg0, wg1, KG, bgi, bgh, gihb, NP);

  for (int s = 0; s < T; ++s) {
    const int cur = s & 1, nxt = (s + 1) & 1;
    gates_kernel<<<dim3(NP / 128, B / 128), 512, 0, stream>>>(
        hA0[cur], hA1[cur], H, wg0, wg1, KG, E, gihb, NP, tokb,
        cbuf, hA0[nxt], hA1[nxt]);
    logits_kernel<<<dim3(V / 128, B / 128), 512, 0, stream>>>(
        hA0[nxt], hA1[nxt], H, wl0, wl1, lpb,
        partM, partI, s, B, V);
    finalize_kernel<<<B, 256, 0, stream>>>(
        partM, partI, out, tokb, s, Tp1, V);
  }
}

// Round 4
// 3778.749 us; speedup vs baseline: 1.3695x; 1.0464x over previous
//
#include <hip/hip_runtime.h>
#include <math.h>

// ---------------------------------------------------------------------------
// Sender: LSTM + Gumbel straight-through decode, 32 steps.
// Round 12 (from r11, 3954 us; r10 3968 — tile change was neutral, so the
// limiter is per-K-step issue/overhead, not off-chip traffic):
//  (1) ONE barrier per K-step (was 2). Safe: reaching iter t's barrier means
//      all waves completed iter t-1's compute, so staging buf (t+3)&3 =
//      (t-1)&3 AFTER the barrier cannot race readers; each wave's own vmcnt
//      wait precedes the barrier, so buf t is fully landed before compute.
//  (2) Stage-issue moved after the barrier -> load issue hides under the
//      MFMA cluster. In-flight: 3 stages -> steady vmcnt(8), tail 8/4/0.
//  (3) K-loop unrolled x4 with COMPILE-TIME buffer indices: LDS fragment
//      addresses fold to base+immediate ds_read offsets; global stage
//      pointers strength-reduce. Kills ~100 VALU/wave/K-step of dynamic
//      addressing that competed with MFMA for the issue port.
// Geometry unchanged from r11: 128x128 tile, 512 thr / 8 waves (wave=32x64),
// BK=32, 4-deep LDS pipeline (128 KB), K-slot XOR swizzle, f16 2-way split
// (3 MFMA/product). All MFMA ops/order and epilogues bit-identical to r11
// (absmax 0.0 there).
// ---------------------------------------------------------------------------

typedef _Float16 f16;
typedef f16 f16x8 __attribute__((ext_vector_type(8)));
typedef float f32x4 __attribute__((ext_vector_type(4)));

#define F16_MIN_NORM 6.104e-5f

__device__ __forceinline__ void split_f16(float v, f16& h, f16& l) {
  f16 h0 = (fabsf(v) < F16_MIN_NORM) ? (f16)0.0f : (f16)v;
  float r = (v - (float)h0) * 4096.0f;
  h = h0; l = (f16)r;
}

__device__ __forceinline__ float sigm(float x) { return 1.0f / (1.0f + expf(-x)); }

#define GLOAD_LDS16(gsrc, ldst)                                               \
  __builtin_amdgcn_global_load_lds(                                           \
      (const __attribute__((address_space(1))) unsigned int*)(const void*)(gsrc), \
      (__attribute__((address_space(3))) unsigned int*)(void*)(ldst), 16, 0, 0)

// --------------------------- threefry / gumbel -----------------------------

__device__ __forceinline__ unsigned tf_rotl(unsigned x, int r) {
  return (x << r) | (x >> (32 - r));
}

// JAX threefry2x32-20, key (0,42), partitionable: draw = x0_out ^ x1_out.
__device__ inline float gumbel_at(unsigned idx) {
  const unsigned ks0 = 0u;
  const unsigned ks1 = 42u;
  const unsigned ks2 = 0x1BD11BDAu ^ ks0 ^ ks1;
  unsigned x0 = 0u + ks0;
  unsigned x1 = idx + ks1;
#define TFR(rot) { x0 += x1; x1 = tf_rotl(x1, rot); x1 ^= x0; }
  TFR(13) TFR(15) TFR(26) TFR(6)
  x0 += ks1; x1 += ks2 + 1u;
  TFR(17) TFR(29) TFR(16) TFR(24)
  x0 += ks2; x1 += ks0 + 2u;
  TFR(13) TFR(15) TFR(26) TFR(6)
  x0 += ks0; x1 += ks1 + 3u;
  TFR(17) TFR(29) TFR(16) TFR(24)
  x0 += ks1; x1 += ks2 + 4u;
  TFR(13) TFR(15) TFR(26) TFR(6)
  x0 += ks2; x1 += ks0 + 5u;
#undef TFR
  const unsigned bits = x0 ^ x1;
  const float f = __uint_as_float((bits >> 9) | 0x3F800000u) - 1.0f;
  const float tiny = 1.17549435082228751e-38f;
  const float u = fmaxf(tiny, f * (1.0f - tiny) + tiny);
  return -logf(-logf(u));
}

// ------------------------- setup / pack kernels ----------------------------

__global__ void init_kernel(float* __restrict__ out, const int* __restrict__ startp,
                            int* __restrict__ tok, int Tp1, int V) {
  const int b = blockIdx.x;
  const int start = *startp;
  if (threadIdx.x == 0) tok[b] = start;
  float* orow = out + (size_t)b * Tp1 * V;
  const int tq = start >> 2;
  for (int v4 = threadIdx.x; v4 < V / 4; v4 += blockDim.x) {
    float4 v = make_float4(0.f, 0.f, 0.f, 0.f);
    if (v4 == tq) ((float*)&v)[start & 3] = 1.0f;
    ((float4*)orow)[v4] = v;
  }
}

// packed gate col p: gate q=(p>>4)&3, unit u=((p>>6)<<4)+(p&15); orig row
// n' = q*H + u. wpk[p][k] = k<E ? wih[n'][k] : whh[n'][k-E], split.
__global__ void pack_gates_kernel(const float* __restrict__ wih,
                                  const float* __restrict__ whh,
                                  f16* __restrict__ w0, f16* __restrict__ w1,
                                  int E, int H, int K) {
  const int k = blockIdx.x * blockDim.x + threadIdx.x;
  const int p = blockIdx.y;
  if (k >= K) return;
  const int n = ((p >> 4) & 3) * H + ((p >> 6) << 4) + (p & 15);
  const float v = (k < E) ? wih[(size_t)n * E + k] : whh[(size_t)n * H + (k - E)];
  f16 h, l; split_f16(v, h, l);
  w0[(size_t)p * K + k] = h;
  w1[(size_t)p * K + k] = l;
}

__global__ void pack_bias_kernel(const float* __restrict__ bih,
                                 const float* __restrict__ bhh,
                                 float* __restrict__ bi, float* __restrict__ bh, int H) {
  const int p = blockIdx.x * blockDim.x + threadIdx.x;
  const int n = ((p >> 4) & 3) * H + ((p >> 6) << 4) + (p & 15);
  bi[p] = bih[n];
  bh[p] = bhh[n];
}

__global__ void split_kernel(const float* __restrict__ in,
                             f16* __restrict__ o0, f16* __restrict__ o1, int n) {
  const int i = blockIdx.x * blockDim.x + threadIdx.x;
  if (i < n) { f16 h, l; split_f16(in[i], h, l); o0[i] = h; o1[i] = l; }
}

// ----------------------- shared K-loop building block ----------------------
// block 512 thr / 8 waves, tile 128x128, BK=32, 4-deep LDS pipeline (128 KB).
// Staging: 32 1KB chunks (A-hi 8, A-lo 8, B-hi 8, B-lo 8), 4 per wave.
// Wave (wr=wid&3, wc=wid>>2) computes rows [wr*32,+32) x cols [wc*64,+64).
// Swizzle: LDS[row][slot] holds global 16B-slot (slot ^ ((row>>1)&3)).
//   stage source slot = (lane&3) ^ ((lane>>3)&3)   (srow = lane>>2)
//   read slot         = (lane>>4) ^ ((lane>>1)&3)  (row & 15 == lane & 15)

__device__ __forceinline__ void stage_chunk(
    int chunk, int srow, int scol,
    const f16* __restrict__ a0s, const f16* __restrict__ a1s, int lda, int ka, int bm,
    const f16* __restrict__ b0s, const f16* __restrict__ b1s, int ldb, int kb, int bn,
    f16 (*ldsA0)[32], f16 (*ldsA1)[32], f16 (*ldsB0)[32], f16 (*ldsB1)[32])
{
  if (chunk < 8) {
    GLOAD_LDS16(a0s + (size_t)(bm + chunk * 16 + srow) * lda + ka + scol,
                &ldsA0[chunk * 16][0]);
  } else if (chunk < 16) {
    const int s = chunk - 8;
    GLOAD_LDS16(a1s + (size_t)(bm + s * 16 + srow) * lda + ka + scol,
                &ldsA1[s * 16][0]);
  } else if (chunk < 24) {
    const int s = chunk - 16;
    GLOAD_LDS16(b0s + (size_t)(bn + s * 16 + srow) * ldb + kb + scol,
                &ldsB0[s * 16][0]);
  } else {
    const int s = chunk - 24;
    GLOAD_LDS16(b1s + (size_t)(bn + s * 16 + srow) * ldb + kb + scol,
                &ldsB1[s * 16][0]);
  }
}

#define MFMA_DECLS                                                            \
  const int tid  = threadIdx.x;                                               \
  const int lane = tid & 63;                                                  \
  const int wid  = tid >> 6;                                                  \
  const int bm   = blockIdx.y * 128;                                          \
  const int bn   = blockIdx.x * 128;                                          \
  const int wm   = (wid & 3) * 32;                                            \
  const int wn   = (wid >> 2) * 64;                                           \
  const int fr   = lane & 15;                                                 \
  const int fk   = (((lane >> 4) ^ ((lane >> 1) & 3)) * 8);                   \
  const int srow = lane >> 2;                                                 \
  const int scol = (((lane & 3) ^ ((lane >> 3) & 3)) * 8);                    \
  f32x4 acc0[2][4], acc1[2][4];                                               \
  _Pragma("unroll") for (int i = 0; i < 2; ++i)                               \
  _Pragma("unroll") for (int j = 0; j < 4; ++j) {                             \
    acc0[i][j] = (f32x4)0.0f; acc1[i][j] = (f32x4)0.0f; }

#define MFMA_LDS_DECL                                                         \
  __shared__ f16 ldsA0[4][128][32], ldsA1[4][128][32],                        \
                 ldsB0[4][128][32], ldsB1[4][128][32];

// Issue-only staging into buffer `buf` (no barriers here).
#define MFMA_STAGE_TO(buf, a0s, a1s, lda, ka, b0s, b1s, ldb, kb)              \
  { _Pragma("unroll") for (int c = 0; c < 4; ++c)                             \
      stage_chunk(wid * 4 + c, srow, scol, (a0s), (a1s), (lda), (ka), bm,     \
                  (b0s), (b1s), (ldb), (kb), bn,                              \
                  ldsA0[(buf)], ldsA1[(buf)], ldsB0[(buf)], ldsB1[(buf)]); }

#define MFMA_COMPUTE_FROM(buf)                                                \
  {                                                                           \
    f16x8 a0[2], a1[2], b0[4], b1[4];                                         \
    _Pragma("unroll") for (int i = 0; i < 2; ++i) {                           \
      a0[i] = *(const f16x8*)&ldsA0[(buf)][wm + i * 16 + fr][fk];             \
      a1[i] = *(const f16x8*)&ldsA1[(buf)][wm + i * 16 + fr][fk];             \
    }                                                                         \
    _Pragma("unroll") for (int j = 0; j < 4; ++j) {                           \
      b0[j] = *(const f16x8*)&ldsB0[(buf)][wn + j * 16 + fr][fk];             \
      b1[j] = *(const f16x8*)&ldsB1[(buf)][wn + j * 16 + fr][fk];             \
    }                                                                         \
    _Pragma("unroll") for (int i = 0; i < 2; ++i)                             \
    _Pragma("unroll") for (int j = 0; j < 4; ++j) {                           \
      acc0[i][j] = __builtin_amdgcn_mfma_f32_16x16x32_f16(a0[i], b0[j], acc0[i][j], 0, 0, 0); \
      acc1[i][j] = __builtin_amdgcn_mfma_f32_16x16x32_f16(a0[i], b1[j], acc1[i][j], 0, 0, 0); \
      acc1[i][j] = __builtin_amdgcn_mfma_f32_16x16x32_f16(a1[i], b0[j], acc1[i][j], 0, 0, 0); \
    }                                                                         \
  }

// One pipeline iteration: counted wait for buf's loads (own chunks), ONE
// barrier (implies all waves landed their chunks for this buf AND finished
// computing the buf that DOSTAGE overwrites), then stage-issue (hidden under
// MFMA), then the MFMA cluster. buf is a compile-time literal.
#define PIPE_ITER(buf, DOSTAGE, VM)                                           \
  asm volatile("s_waitcnt vmcnt(" #VM ")" ::: "memory");                      \
  __builtin_amdgcn_s_barrier();                                               \
  asm volatile("" ::: "memory");                                              \
  DOSTAGE                                                                     \
  asm volatile("" ::: "memory");                                              \
  __builtin_amdgcn_s_setprio(1);                                              \
  MFMA_COMPUTE_FROM(buf)                                                      \
  __builtin_amdgcn_s_setprio(0);                                              \
  asm volatile("" ::: "memory");

// 4-deep pipeline, unrolled x4 (NT must be a multiple of 4, NT >= 8).
// STAGE_T(buf, t) must be #defined per kernel; buf/t are compile-time-
// friendly expressions (buf literal; t = tt + const).
#define PIPE(NT)                                                              \
  STAGE_T(0, 0) STAGE_T(1, 1) STAGE_T(2, 2)                                   \
  {                                                                           \
    int tt = 0;                                                               \
    for (; tt + 4 < (NT); tt += 4) {                                          \
      PIPE_ITER(0, STAGE_T(3, tt + 3), 8)                                     \
      PIPE_ITER(1, STAGE_T(0, tt + 4), 8)                                     \
      PIPE_ITER(2, STAGE_T(1, tt + 5), 8)                                     \
      PIPE_ITER(3, STAGE_T(2, tt + 6), 8)                                     \
    }                                                                         \
    PIPE_ITER(0, STAGE_T(3, tt + 3), 8)                                       \
    PIPE_ITER(1, {}, 8)                                                       \
    PIPE_ITER(2, {}, 4)                                                       \
    PIPE_ITER(3, {}, 0)                                                       \
  }

// ------------------- h0 GEMM: h0 = t @ aff_w^T + aff_b ---------------------
__global__ __launch_bounds__(512, 2) void h0_kernel(
    const f16* __restrict__ t0, const f16* __restrict__ t1, int F,
    const f16* __restrict__ aw0, const f16* __restrict__ aw1,
    const float* __restrict__ affb,
    f16* __restrict__ h0p, f16* __restrict__ h1p, int H,
    float* __restrict__ czero)
{
  MFMA_LDS_DECL
  MFMA_DECLS
  const int NT = F / 32;
#define STAGE_T(buf, t) MFMA_STAGE_TO(buf, t0, t1, F, (t) * 32, aw0, aw1, F, (t) * 32)
  PIPE(NT)
#undef STAGE_T
  const int q4 = (lane >> 4) * 4;
  const float s12 = 1.0f / 4096.0f;
  const int cn0 = bn + wn;
#pragma unroll
  for (int j = 0; j < 4; ++j) {
    const int col = cn0 + j * 16 + fr;
    const float bb = affb[col];
#pragma unroll
    for (int i = 0; i < 2; ++i) {
#pragma unroll
      for (int r = 0; r < 4; ++r) {
        const int row = bm + wm + i * 16 + q4 + r;
        const float v = (acc0[i][j][r] + acc1[i][j][r] * s12) + bb;
        f16 hh, hl; split_f16(v, hh, hl);
        const size_t off = (size_t)row * H + col;
        h0p[off] = hh; h1p[off] = hl;
        czero[off] = 0.0f;
      }
    }
  }
}

// ------- gih table GEMM: gih[v][p] = emb[v].wih[n(p)] + bih + bhh ----------
__global__ __launch_bounds__(512, 2) void gih_kernel(
    const f16* __restrict__ e0, const f16* __restrict__ e1, int E,
    const f16* __restrict__ w0, const f16* __restrict__ w1, int K,
    const float* __restrict__ bi, const float* __restrict__ bh,
    float* __restrict__ gih, int NP)
{
  MFMA_LDS_DECL
  MFMA_DECLS
  const int NT = E / 32;
#define STAGE_T(buf, t) MFMA_STAGE_TO(buf, e0, e1, E, (t) * 32, w0, w1, K, (t) * 32)
  PIPE(NT)
#undef STAGE_T
  const int q4 = (lane >> 4) * 4;
  const float s12 = 1.0f / 4096.0f;
  const int cn0 = bn + wn;
#pragma unroll
  for (int j = 0; j < 4; ++j) {
    const int col = cn0 + j * 16 + fr;
    const float bb = bi[col] + bh[col];
#pragma unroll
    for (int i = 0; i < 2; ++i)
#pragma unroll
      for (int r = 0; r < 4; ++r) {
        const int row = bm + wm + i * 16 + q4 + r;
        gih[(size_t)row * NP + col] = (acc0[i][j][r] + acc1[i][j][r] * s12) + bb;
      }
  }
}

// ---------------- gates GEMM + fused LSTM cell epilogue --------------------
// gates = h @ w_hh^T (K=H) + gih[tok[row]] (embedding term + both biases).
__global__ __launch_bounds__(512, 2) void gates_kernel(
    const f16* __restrict__ hin0, const f16* __restrict__ hin1, int H,
    const f16* __restrict__ w0, const f16* __restrict__ w1, int K, int E,
    const float* __restrict__ gih, int NP, const int* __restrict__ tok,
    float* __restrict__ cbuf,
    f16* __restrict__ hout0, f16* __restrict__ hout1)
{
  MFMA_LDS_DECL
  MFMA_DECLS
  const int NT = H / 32;
#define STAGE_T(buf, t) MFMA_STAGE_TO(buf, hin0, hin1, H, (t) * 32, w0, w1, K, E + (t) * 32)
  PIPE(NT)
#undef STAGE_T
  // epilogue: packed cols -> unit u = (cn0>>2)+fr, gate q = j.
  const int q4 = (lane >> 4) * 4;
  const float s12 = 1.0f / 4096.0f;
  const int cn0 = bn + wn;
  const int nunit = (cn0 >> 2) + fr;
#pragma unroll
  for (int i = 0; i < 2; ++i) {
#pragma unroll
    for (int r = 0; r < 4; ++r) {
      const int row = bm + wm + i * 16 + q4 + r;
      const float* gr = gih + (size_t)tok[row] * NP + cn0 + fr;
      float gv[4];
#pragma unroll
      for (int j = 0; j < 4; ++j)
        gv[j] = (acc0[i][j][r] + acc1[i][j][r] * s12) + gr[j * 16];
      const size_t off = (size_t)row * H + nunit;
      const float c = cbuf[off];
      const float cn = __fadd_rn(__fmul_rn(sigm(gv[1]), c),
                                 __fmul_rn(sigm(gv[0]), tanhf(gv[2])));
      const float hn = __fmul_rn(sigm(gv[3]), tanhf(cn));
      cbuf[off] = cn;
      f16 hh, hl; split_f16(hn, hh, hl);
      hout0[off] = hh; hout1[off] = hl;
    }
  }
}

// ------------- logits GEMM + fused argmax-partials epilogue ----------------
__global__ __launch_bounds__(512, 2) void logits_kernel(
    const f16* __restrict__ h0p, const f16* __restrict__ h1p, int H,
    const f16* __restrict__ w0, const f16* __restrict__ w1,
    const float* __restrict__ lpb,
    float* __restrict__ partM, int* __restrict__ partI,
    int step, int B, int V)
{
  MFMA_LDS_DECL
  MFMA_DECLS
  const int NT = H / 32;
#define STAGE_T(buf, t) MFMA_STAGE_TO(buf, h0p, h1p, H, (t) * 32, w0, w1, H, (t) * 32)
  PIPE(NT)
#undef STAGE_T
  const int q4 = (lane >> 4) * 4;
  const float s12 = 1.0f / 4096.0f;
  const int cn0 = bn + wn;
  float bv[4];
#pragma unroll
  for (int j = 0; j < 4; ++j) bv[j] = lpb[cn0 + j * 16 + fr];
  // w = logit + gumbel, overwrite acc0
#pragma unroll
  for (int i = 0; i < 2; ++i)
#pragma unroll
    for (int j = 0; j < 4; ++j) {
      const int col = cn0 + j * 16 + fr;
#pragma unroll
      for (int r = 0; r < 4; ++r) {
        const int row = bm + wm + i * 16 + q4 + r;
        const float logit = (acc0[i][j][r] + acc1[i][j][r] * s12) + bv[j];
        const unsigned gidx = ((unsigned)(step * B + row)) * (unsigned)V + (unsigned)col;
        acc0[i][j][r] = logit + gumbel_at(gidx);
      }
    }
  // per-row argmax over this wave's 64 cols (within each 16-lane group).
  // sc == 1.0 exactly, so no denominator partials needed.
  const int grp = cn0 >> 6;   // 64 col-groups of 64
#pragma unroll
  for (int i = 0; i < 2; ++i) {
#pragma unroll
    for (int r = 0; r < 4; ++r) {
      float mx = -INFINITY; int ix = 0;
#pragma unroll
      for (int j = 0; j < 4; ++j) {
        const float w = acc0[i][j][r];
        const int col = cn0 + j * 16 + fr;
        if (w > mx) { mx = w; ix = col; }
      }
#pragma unroll
      for (int m = 1; m < 16; m <<= 1) {
        const float om = __shfl_xor(mx, m, 64);
        const int oi = __shfl_xor(ix, m, 64);
        if (om > mx || (om == mx && oi < ix)) { mx = om; ix = oi; }
      }
      if (fr == 0) {
        const int row = bm + wm + i * 16 + q4 + r;
        partM[(size_t)row * 64 + grp] = mx;
        partI[(size_t)row * 64 + grp] = ix;
      }
    }
  }
}

// ----------- finalize: argmax reduce, write one-hot, publish tok -----------
__global__ __launch_bounds__(256) void finalize_kernel(
    const float* __restrict__ partM, const int* __restrict__ partI,
    float* __restrict__ out, int* __restrict__ tok,
    int step, int Tp1, int V)
{
  const int b = blockIdx.x;
  const int tid = threadIdx.x;
  __shared__ int s_tok;

  if (tid < 64) {
    float mx = partM[(size_t)b * 64 + tid];
    int ix = partI[(size_t)b * 64 + tid];
#pragma unroll
    for (int m = 1; m < 64; m <<= 1) {
      const float om = __shfl_xor(mx, m, 64);
      const int oi = __shfl_xor(ix, m, 64);
      if (om > mx || (om == mx && oi < ix)) { mx = om; ix = oi; }
    }
    if (tid == 0) { s_tok = ix; tok[b] = ix; }
  }
  __syncthreads();
  const int tk = s_tok;

  // one-hot write with exact 1.0 (sc == (1-y)+y == 1.0f identically)
  float* orow = out + ((size_t)b * Tp1 + step + 1) * V;
  const int tq = tk >> 2;
#pragma unroll
  for (int j = 0; j < 4; ++j) {
    const int idx = tid + 256 * j;
    float4 v = make_float4(0.f, 0.f, 0.f, 0.f);
    if (idx == tq) ((float*)&v)[tk & 3] = 1.0f;
    ((float4*)orow)[idx] = v;
  }
}

// ------------------------------- host side ---------------------------------

extern "C" void kernel_launch(void* const* d_in, const int* in_sizes, int n_in,
                              void* d_out, int out_size, void* d_ws, size_t ws_size,
                              hipStream_t stream) {
  const float* t     = (const float*)d_in[0];
  const float* emb   = (const float*)d_in[1];
  const float* affw  = (const float*)d_in[2];
  const float* affb  = (const float*)d_in[3];
  const float* wih   = (const float*)d_in[4];
  const float* whh   = (const float*)d_in[5];
  const float* bih   = (const float*)d_in[6];
  const float* bhh   = (const float*)d_in[7];
  const float* lpw   = (const float*)d_in[8];
  const float* lpb   = (const float*)d_in[9];
  const int*   start = (const int*)d_in[10];
  float* out = (float*)d_out;

  const int H = in_sizes[3];             // 1024
  const int V = in_sizes[9];             // 4096
  const int E = in_sizes[1] / V;         // 256
  const int F = in_sizes[2] / H;         // 2048
  const int B = in_sizes[0] / F;         // 1024
  const int Tp1 = out_size / (B * V);    // 33
  const int T = Tp1 - 1;                 // 32
  const int KG = E + H;                  // 1280
  const int NP = 4 * H;                  // 4096 packed gate cols

  // ---- workspace layout (~190 MB) ----
  char* p = (char*)d_ws;
  float* gihb  = (float*)p; p += (size_t)V * NP * 4;          // 64 MB gih table
  float* cbuf  = (float*)p; p += (size_t)B * H * 4;           // 4 MB
  f16* hA0[2]; f16* hA1[2];
  hA0[0] = (f16*)p; p += (size_t)B * H * 2;
  hA1[0] = (f16*)p; p += (size_t)B * H * 2;
  hA0[1] = (f16*)p; p += (size_t)B * H * 2;
  hA1[1] = (f16*)p; p += (size_t)B * H * 2;                   // 8 MB
  f16* wg0 = (f16*)p; p += (size_t)V * KG * 2;                // 21 MB packed gates
  f16* wg1 = (f16*)p; p += (size_t)V * KG * 2;
  f16* wl0 = (f16*)p; p += (size_t)V * H * 2;                 // 16 MB lp_w
  f16* wl1 = (f16*)p; p += (size_t)V * H * 2;
  f16* t0  = (f16*)p; p += (size_t)B * F * 2;                 // 8 MB t planes
  f16* t1  = (f16*)p; p += (size_t)B * F * 2;
  f16* aw0 = (f16*)p; p += (size_t)H * F * 2;                 // 8 MB aff_w planes
  f16* aw1 = (f16*)p; p += (size_t)H * F * 2;
  f16* em0 = (f16*)p; p += (size_t)V * E * 2;                 // 4 MB emb planes
  f16* em1 = (f16*)p; p += (size_t)V * E * 2;
  float* bgi = (float*)p; p += (size_t)NP * 4;
  float* bgh = (float*)p; p += (size_t)NP * 4;
  float* partM = (float*)p; p += (size_t)B * 64 * 4;
  int*   partI = (int*)p;   p += (size_t)B * 64 * 4;
  int*   tokb  = (int*)p;   p += (size_t)B * 4;
  (void)ws_size; (void)n_in;

  // ---- setup ----
  init_kernel<<<B, 256, 0, stream>>>(out, start, tokb, Tp1, V);
  pack_gates_kernel<<<dim3((KG + 255) / 256, NP), 256, 0, stream>>>(
      wih, whh, wg0, wg1, E, H, KG);
  pack_bias_kernel<<<NP / 256, 256, 0, stream>>>(bih, bhh, bgi, bgh, H);
  split_kernel<<<(V * H + 255) / 256, 256, 0, stream>>>(lpw, wl0, wl1, V * H);
  split_kernel<<<(B * F + 255) / 256, 256, 0, stream>>>(t, t0, t1, B * F);
  split_kernel<<<(H * F + 255) / 256, 256, 0, stream>>>(affw, aw0, aw1, H * F);
  split_kernel<<<(V * E + 255) / 256, 256, 0, stream>>>(emb, em0, em1, V * E);
  // h0 = t @ aff_w^T + aff_b -> split into hA[0]; zero cbuf
  h0_kernel<<<dim3(H / 128, B / 128), 512, 0, stream>>>(
      t0, t1, F, aw0, aw1, affb, hA0[0], hA1[0], H, cbuf);
  // gih = emb @ w_ih^T + b_ih + b_hh (packed cols), f32
  gih_kernel<<<dim3(NP / 128, V / 128), 512, 0, stream>>>(
      em0, em1, E, wg0, wg1, KG, bgi, bgh, gihb, NP);

  for (int s = 0; s < T; ++s) {
    const int cur = s & 1, nxt = (s + 1) & 1;
    gates_kernel<<<dim3(NP / 128, B / 128), 512, 0, stream>>>(
        hA0[cur], hA1[cur], H, wg0, wg1, KG, E, gihb, NP, tokb,
        cbuf, hA0[nxt], hA1[nxt]);
    logits_kernel<<<dim3(V / 128, B / 128), 512, 0, stream>>>(
        hA0[nxt], hA1[nxt], H, wl0, wl1, lpb,
        partM, partI, s, B, V);
    finalize_kernel<<<B, 256, 0, stream>>>(
        partM, partI, out, tokb, s, Tp1, V);
  }
}